// Round 6
// baseline (185.198 us; speedup 1.0000x reference)
//
#include <hip/hip_runtime.h>
#include <stdint.h>

#define B_   200
#define N0   65536
#define COLS (N0 * 3)
#define JT   32
#define TPAD 204

// ---------------- Threefry-2x32 (JAX-compatible, 20 rounds) ----------------
__host__ __device__ static inline void tf2x32(uint32_t k0, uint32_t k1,
                                              uint32_t x0, uint32_t x1,
                                              uint32_t& o0, uint32_t& o1) {
  const uint32_t ks2 = k0 ^ k1 ^ 0x1BD11BDAu;
  x0 += k0; x1 += k1;
#define TF_R(r) { x0 += x1; x1 = (x1 << (r)) | (x1 >> (32 - (r))); x1 ^= x0; }
  TF_R(13) TF_R(15) TF_R(26) TF_R(6)   x0 += k1;  x1 += ks2 + 1u;
  TF_R(17) TF_R(29) TF_R(16) TF_R(24)  x0 += ks2; x1 += k0  + 2u;
  TF_R(13) TF_R(15) TF_R(26) TF_R(6)   x0 += k0;  x1 += k1  + 3u;
  TF_R(17) TF_R(29) TF_R(16) TF_R(24)  x0 += k1;  x1 += ks2 + 4u;
  TF_R(13) TF_R(15) TF_R(26) TF_R(6)   x0 += ks2; x1 += k0  + 5u;
#undef TF_R
  o0 = x0; o1 = x1;
}

// ---------------- all row_ptrs in one kernel (+ zero KL slot) ----------------
__global__ void build_rp_all(const int* __restrict__ dst0, const int* __restrict__ dst1,
                             const int* __restrict__ dst2, const int* __restrict__ dst3,
                             const int* __restrict__ dst4,
                             int* rp0, int* rp1, int* rp2, int* rp3, int* rp4,
                             float* kl) {
  int tid = blockIdx.x * blockDim.x + threadIdx.x;
  if (tid == 0) *kl = 0.f;
  if (tid >= 21829) return;
  const int starts[6] = {0, 16385, 20482, 21507, 21764, 21829};
  const int EDGa[5]   = {147456, 36864, 9216, 2304, 576};
  const int* dsts[5]  = {dst0, dst1, dst2, dst3, dst4};
  int* rps[5]         = {rp0, rp1, rp2, rp3, rp4};
  int l = 0;
  while (tid >= starts[l + 1]) ++l;
  int c = tid - starts[l];
  const int* dst = dsts[l];
  int lo = 0, hi = EDGa[l];
  while (lo < hi) { int mid = (lo + hi) >> 1; if (dst[mid] < c) lo = mid + 1; else hi = mid; }
  rps[l][c] = lo;
}

// ---------------- KL over all 5 weight tensors, one kernel ----------------
__global__ __launch_bounds__(256) void kl_all_kernel(
    const float* __restrict__ w0, const float* __restrict__ w1,
    const float* __restrict__ w2, const float* __restrict__ w3,
    const float* __restrict__ w4, float* __restrict__ out) {
  __shared__ float red[256];
  const float* ws[5] = {w0, w1, w2, w3, w4};
  const int    ns[5] = {442368, 36864, 9216, 2304, 576};
  int stride = gridDim.x * blockDim.x;
  int tid0 = blockIdx.x * blockDim.x + threadIdx.x;
  float s = 0.f;
#pragma unroll
  for (int l = 0; l < 5; ++l) {
    const float* w = ws[l];
    int n = ns[l];
    for (int i = tid0; i < n; i += stride) {
      float v = w[i];
      s += fmaf(0.5f * v, v, 999.5f);      // 0.5*(w*w-1) - (-1000)
    }
  }
  red[threadIdx.x] = s;
  __syncthreads();
  for (int st = 128; st > 0; st >>= 1) {
    if (threadIdx.x < st) red[threadIdx.x] += red[threadIdx.x + st];
    __syncthreads();
  }
  if (threadIdx.x == 0) atomicAdd(out, red[0]);
}

// ---------------- transpose: 32 j-cols x ALL 200 b, 512 threads ----------------
// 3 unconditional float4 loads (rows bl, bl+64, bl+128 all < 200) + wave-0-
// uniform tail -> 4 global_load_dwordx4 in flight per thread (MLP fix).
// ds_write component order rotated by lane group g -> 2-way banks (free).
// TPAD=204 keeps LDS rows 16B-aligned -> conflict-free b128 read phase.
__global__ __launch_bounds__(512, 8) void transpose_rows_kernel(
    const float* __restrict__ x, float* __restrict__ xT) {
  __shared__ float tile[JT][TPAD];
  const int t  = threadIdx.x;              // 0..511
  const int j0 = blockIdx.x * JT;
  const int bl = t >> 3;                   // 0..63
  const int jj = (t & 7) << 2;             // 0,4,...,28
  const int g  = (t >> 3) & 3;             // write-order rotation

  const float* xp = x + j0 + jj;
  float4 v0 = *(const float4*)(xp + (size_t)(bl      ) * COLS);
  float4 v1 = *(const float4*)(xp + (size_t)(bl +  64) * COLS);
  float4 v2 = *(const float4*)(xp + (size_t)(bl + 128) * COLS);
  float4 v3;
  if (t < 64) v3 = *(const float4*)(xp + (size_t)(bl + 192) * COLS);

  auto comp = [](const float4& v, int s) {
    return s == 0 ? v.x : s == 1 ? v.y : s == 2 ? v.z : v.w;
  };
#pragma unroll
  for (int k = 0; k < 4; ++k) {
    int s = (k + g) & 3;                   // rotated order: banks spread, placement unchanged
    tile[jj + s][bl      ] = comp(v0, s);
    tile[jj + s][bl +  64] = comp(v1, s);
    tile[jj + s][bl + 128] = comp(v2, s);
  }
  if (t < 64) {
#pragma unroll
    for (int k = 0; k < 4; ++k) {
      int s = (k + g) & 3;
      tile[jj + s][bl + 192] = comp(v3, s);
    }
  }
  __syncthreads();
  // 32 rows x 50 float4 = 1600 aligned 16B stores, full density
#pragma unroll
  for (int q = 0; q < 4; ++q) {
    unsigned idx = (unsigned)t + ((unsigned)q << 9);
    if (idx < 1600u) {
      unsigned row = idx / 50u;            // magic-mul, unsigned
      unsigned col = (idx - row * 50u) << 2;
      float4 o = *(const float4*)&tile[row][col];
      *(float4*)(xT + (size_t)(j0 + row) * B_ + col) = o;
    }
  }
}

// ---------------- layer-1 pool + BN + ReLU + dropout (fused) ----------------
__global__ __launch_bounds__(256) void pool1_bn_kernel(
    const float* __restrict__ xT, const float* __restrict__ x,
    const int* __restrict__ src, const float* __restrict__ w,
    const float* __restrict__ bias, const int* __restrict__ rp,
    const float* __restrict__ gamma, const float* __restrict__ beta,
    float* __restrict__ out, int cpc, int use_t, uint32_t k0, uint32_t k1) {
  __shared__ float red[4][2];
  __shared__ float bcast[2];
  int b = threadIdx.x;
  int bl = b < B_ ? b : B_ - 1;
  bool valid = b < B_;
  int c0 = blockIdx.x * cpc;
  for (int cc = 0; cc < cpc; ++cc) {
    int c = c0 + cc;
    float acc = bias[c];
    int e1 = rp[c + 1];
    if (use_t) {
      for (int e = rp[c]; e < e1; ++e) {
        int s = src[e];
        const float* xp = xT + (size_t)s * (3 * B_) + bl;
        acc = fmaf(xp[0],      w[3 * e],     acc);
        acc = fmaf(xp[B_],     w[3 * e + 1], acc);
        acc = fmaf(xp[2 * B_], w[3 * e + 2], acc);
      }
    } else {
      for (int e = rp[c]; e < e1; ++e) {
        int s = src[e];
        const float* xp = x + ((size_t)bl * N0 + s) * 3;
        acc = fmaf(xp[0], w[3 * e],     acc);
        acc = fmaf(xp[1], w[3 * e + 1], acc);
        acc = fmaf(xp[2], w[3 * e + 2], acc);
      }
    }
    float sv = valid ? acc : 0.f;
    float qv = valid ? acc * acc : 0.f;
#pragma unroll
    for (int off = 32; off; off >>= 1) { sv += __shfl_xor(sv, off); qv += __shfl_xor(qv, off); }
    int wid = threadIdx.x >> 6;
    if ((threadIdx.x & 63) == 0) { red[wid][0] = sv; red[wid][1] = qv; }
    __syncthreads();
    if (threadIdx.x == 0) {
      float s2 = red[0][0] + red[1][0] + red[2][0] + red[3][0];
      float q2 = red[0][1] + red[1][1] + red[2][1] + red[3][1];
      float m   = s2 * (1.f / 200.f);
      float var = fmaf(q2, 1.f / 200.f, -m * m);
      float scale = gamma[c] * rsqrtf(var + 1e-5f);
      bcast[0] = scale;
      bcast[1] = fmaf(-m, scale, beta[c]);
    }
    __syncthreads();
    if (valid) {
      float hn = fmaxf(fmaf(acc, bcast[0], bcast[1]), 0.f);
      uint32_t idxf = (uint32_t)b * 16384u + (uint32_t)c;
      uint32_t o0, o1;
      tf2x32(k0, k1, 0u, idxf, o0, o1);
      uint32_t bits = o0 ^ o1;
      float u = __uint_as_float((bits >> 9) | 0x3f800000u) - 1.0f;
      out[(size_t)c * B_ + b] = (u < 0.9f) ? hn * (1.0f / 0.9f) : 0.0f;
    }
    __syncthreads();                       // red/bcast reused next channel
  }
}

// ---------------- layers 2..5 pool (+ optional BN/dropout), (c,b) layout ----------------
__global__ __launch_bounds__(256) void pooln_bn_kernel(
    const float* __restrict__ hin, const int* __restrict__ src,
    const float* __restrict__ w, const float* __restrict__ bias,
    const int* __restrict__ rp, const float* __restrict__ gamma,
    const float* __restrict__ beta, float* __restrict__ out,
    int cpc, int nout, int has_bn, uint32_t k0, uint32_t k1) {
  __shared__ float red[4][2];
  __shared__ float bcast[2];
  int b = threadIdx.x;
  int bl = b < B_ ? b : B_ - 1;
  bool valid = b < B_;
  int c0 = blockIdx.x * cpc;
  for (int cc = 0; cc < cpc; ++cc) {
    int c = c0 + cc;
    float acc = bias[c];
    int e1 = rp[c + 1];
    for (int e = rp[c]; e < e1; ++e)
      acc = fmaf(hin[(size_t)src[e] * B_ + bl], w[e], acc);
    if (has_bn) {
      float sv = valid ? acc : 0.f;
      float qv = valid ? acc * acc : 0.f;
#pragma unroll
      for (int off = 32; off; off >>= 1) { sv += __shfl_xor(sv, off); qv += __shfl_xor(qv, off); }
      int wid = threadIdx.x >> 6;
      if ((threadIdx.x & 63) == 0) { red[wid][0] = sv; red[wid][1] = qv; }
      __syncthreads();
      if (threadIdx.x == 0) {
        float s2 = red[0][0] + red[1][0] + red[2][0] + red[3][0];
        float q2 = red[0][1] + red[1][1] + red[2][1] + red[3][1];
        float m   = s2 * (1.f / 200.f);
        float var = fmaf(q2, 1.f / 200.f, -m * m);
        float scale = gamma[c] * rsqrtf(var + 1e-5f);
        bcast[0] = scale;
        bcast[1] = fmaf(-m, scale, beta[c]);
      }
      __syncthreads();
      if (valid) {
        float hn = fmaxf(fmaf(acc, bcast[0], bcast[1]), 0.f);
        uint32_t idxf = (uint32_t)b * (uint32_t)nout + (uint32_t)c;
        uint32_t o0, o1;
        tf2x32(k0, k1, 0u, idxf, o0, o1);
        uint32_t bits = o0 ^ o1;
        float u = __uint_as_float((bits >> 9) | 0x3f800000u) - 1.0f;
        out[(size_t)c * B_ + b] = (u < 0.9f) ? hn * (1.0f / 0.9f) : 0.0f;
      }
      __syncthreads();
    } else {
      if (valid) out[(size_t)b * 64 + c] = acc;   // final layer -> (B, 64)
    }
  }
}

// ---------------- host ----------------
extern "C" void kernel_launch(void* const* d_in, const int* in_sizes, int n_in,
                              void* d_out, int out_size, void* d_ws, size_t ws_size,
                              hipStream_t stream) {
  (void)in_sizes; (void)n_in; (void)out_size;
  const float* x = (const float*)d_in[0];
  const int*   src[5]; const int* dst[5];
  const float* w[5];   const float* bias[5];
  const float* gamma[4]; const float* beta[4];
  int idx = 1;
  for (int l = 0; l < 5; ++l) {
    src[l]  = (const int*)d_in[idx++];
    dst[l]  = (const int*)d_in[idx++];
    w[l]    = (const float*)d_in[idx++];
    bias[l] = (const float*)d_in[idx++];
    if (l < 4) { gamma[l] = (const float*)d_in[idx++]; beta[l] = (const float*)d_in[idx++]; }
  }
  static const int NOUT[5] = {16384, 4096, 1024, 256, 64};

  // dkeys = jax.random.split(key(42), 4), partitionable threefry semantics
  uint32_t dk0[4], dk1[4];
  for (uint32_t i = 0; i < 4; ++i) tf2x32(0u, 42u, 0u, i, dk0[i], dk1[i]);

  // workspace carve
  char* ws = (char*)d_ws;
  size_t off = 0;
  auto carve = [&](size_t bytes) -> void* {
    void* p = ws + off;
    off = (off + bytes + 255) & ~(size_t)255;
    return p;
  };
  int* rp[5];
  for (int l = 0; l < 5; ++l) rp[l] = (int*)carve((size_t)(NOUT[l] + 1) * sizeof(int));
  float* bufA = (float*)carve((size_t)16384 * B_ * sizeof(float));
  float* bufB = (float*)carve((size_t)16384 * B_ * sizeof(float));
  float* xT   = (float*)carve((size_t)COLS * B_ * sizeof(float));
  int use_t = (off <= ws_size) ? 1 : 0;

  float* kl = (float*)d_out + 12800;

  // 1: all row pointers + zero KL
  build_rp_all<<<(21829 + 255) / 256, 256, 0, stream>>>(
      dst[0], dst[1], dst[2], dst[3], dst[4],
      rp[0], rp[1], rp[2], rp[3], rp[4], kl);

  // 2: KL reduction (all layers)
  kl_all_kernel<<<256, 256, 0, stream>>>(w[0], w[1], w[2], w[3], w[4], kl);

  // 3: transpose (full-row tiles, 512 threads, MLP-fixed)
  if (use_t)
    transpose_rows_kernel<<<COLS / JT, 512, 0, stream>>>(x, xT);

  // 4: layer 1 (pool + BN + ReLU + dropout)
  pool1_bn_kernel<<<16384 / 8, 256, 0, stream>>>(
      xT, x, src[0], w[0], bias[0], rp[0], gamma[0], beta[0], bufA, 8, use_t,
      dk0[0], dk1[0]);

  // 5-7: layers 2..4 (pool + BN + ReLU + dropout)
  pooln_bn_kernel<<<4096 / 4, 256, 0, stream>>>(
      bufA, src[1], w[1], bias[1], rp[1], gamma[1], beta[1], bufB, 4, 4096, 1,
      dk0[1], dk1[1]);
  pooln_bn_kernel<<<1024 / 2, 256, 0, stream>>>(
      bufB, src[2], w[2], bias[2], rp[2], gamma[2], beta[2], bufA, 2, 1024, 1,
      dk0[2], dk1[2]);
  pooln_bn_kernel<<<256, 256, 0, stream>>>(
      bufA, src[3], w[3], bias[3], rp[3], gamma[3], beta[3], bufB, 1, 256, 1,
      dk0[3], dk1[3]);

  // 8: layer 5 -> d_out (B, 64)
  pooln_bn_kernel<<<64, 256, 0, stream>>>(
      bufB, src[4], w[4], bias[4], rp[4], nullptr, nullptr, (float*)d_out, 1, 64, 0,
      0u, 0u);
}

// Round 7
// 184.976 us; speedup vs baseline: 1.0012x; 1.0012x over previous
//
#include <hip/hip_runtime.h>
#include <stdint.h>

#define B_   200
#define N0   65536
#define COLS (N0 * 3)
#define JT   32
#define TPAD 224

// ---------------- Threefry-2x32 (JAX-compatible, 20 rounds) ----------------
__host__ __device__ static inline void tf2x32(uint32_t k0, uint32_t k1,
                                              uint32_t x0, uint32_t x1,
                                              uint32_t& o0, uint32_t& o1) {
  const uint32_t ks2 = k0 ^ k1 ^ 0x1BD11BDAu;
  x0 += k0; x1 += k1;
#define TF_R(r) { x0 += x1; x1 = (x1 << (r)) | (x1 >> (32 - (r))); x1 ^= x0; }
  TF_R(13) TF_R(15) TF_R(26) TF_R(6)   x0 += k1;  x1 += ks2 + 1u;
  TF_R(17) TF_R(29) TF_R(16) TF_R(24)  x0 += ks2; x1 += k0  + 2u;
  TF_R(13) TF_R(15) TF_R(26) TF_R(6)   x0 += k0;  x1 += k1  + 3u;
  TF_R(17) TF_R(29) TF_R(16) TF_R(24)  x0 += k1;  x1 += ks2 + 4u;
  TF_R(13) TF_R(15) TF_R(26) TF_R(6)   x0 += ks2; x1 += k0  + 5u;
#undef TF_R
  o0 = x0; o1 = x1;
}

// ---------------- all row_ptrs in one kernel (+ zero KL slot) ----------------
__global__ void build_rp_all(const int* __restrict__ dst0, const int* __restrict__ dst1,
                             const int* __restrict__ dst2, const int* __restrict__ dst3,
                             const int* __restrict__ dst4,
                             int* rp0, int* rp1, int* rp2, int* rp3, int* rp4,
                             float* kl) {
  int tid = blockIdx.x * blockDim.x + threadIdx.x;
  if (tid == 0) *kl = 0.f;
  if (tid >= 21829) return;
  const int starts[6] = {0, 16385, 20482, 21507, 21764, 21829};
  const int EDGa[5]   = {147456, 36864, 9216, 2304, 576};
  const int* dsts[5]  = {dst0, dst1, dst2, dst3, dst4};
  int* rps[5]         = {rp0, rp1, rp2, rp3, rp4};
  int l = 0;
  while (tid >= starts[l + 1]) ++l;
  int c = tid - starts[l];
  const int* dst = dsts[l];
  int lo = 0, hi = EDGa[l];
  while (lo < hi) { int mid = (lo + hi) >> 1; if (dst[mid] < c) lo = mid + 1; else hi = mid; }
  rps[l][c] = lo;
}

// ---------------- KL over all 5 weight tensors, one kernel ----------------
__global__ __launch_bounds__(256) void kl_all_kernel(
    const float* __restrict__ w0, const float* __restrict__ w1,
    const float* __restrict__ w2, const float* __restrict__ w3,
    const float* __restrict__ w4, float* __restrict__ out) {
  __shared__ float red[256];
  const float* ws[5] = {w0, w1, w2, w3, w4};
  const int    ns[5] = {442368, 36864, 9216, 2304, 576};
  int stride = gridDim.x * blockDim.x;
  int tid0 = blockIdx.x * blockDim.x + threadIdx.x;
  float s = 0.f;
#pragma unroll
  for (int l = 0; l < 5; ++l) {
    const float* w = ws[l];
    int n = ns[l];
    for (int i = tid0; i < n; i += stride) {
      float v = w[i];
      s += fmaf(0.5f * v, v, 999.5f);      // 0.5*(w*w-1) - (-1000)
    }
  }
  red[threadIdx.x] = s;
  __syncthreads();
  for (int st = 128; st > 0; st >>= 1) {
    if (threadIdx.x < st) red[threadIdx.x] += red[threadIdx.x + st];
    __syncthreads();
  }
  if (threadIdx.x == 0) atomicAdd(out, red[0]);
}

// ---------------- transpose: 32 j-cols x ALL 200 b, 512 threads ----------------
// XOR-swizzled LDS: addr(j,b) = j*TPAD + (b ^ (j&28)).  For this lane's four
// rows j=jj..jj+3 (jj mult of 4), j&28 == jj, so one swizzled index per b.
// Per-wave write banks: (bl ^ jj) mod 32 -> exact 2-way (free).  Bijective &
// self-inverse: read phase uses col ^ (row&28) (float4-contiguous: swz has no
// bits 0-1).  TPAD=224 so b in [192,200) ^ jj stays < 224 (no aliasing).
// 4 UNCONDITIONAL float4 loads (row3 clamped to 199) -> 4 loads in flight.
__global__ __launch_bounds__(512, 4) void transpose_rows_kernel(
    const float* __restrict__ x, float* __restrict__ xT) {
  __shared__ float tile[JT * TPAD];
  const int t  = threadIdx.x;              // 0..511
  const int j0 = blockIdx.x * JT;
  const int bl = t >> 3;                   // 0..63
  const int jj = (t & 7) << 2;             // 0,4,...,28

  const float* xp = x + j0 + jj;
  const int b3 = bl + 192 < B_ ? bl + 192 : B_ - 1;   // clamp, load always
  float4 v0 = *(const float4*)(xp + (size_t)(bl      ) * COLS);
  float4 v1 = *(const float4*)(xp + (size_t)(bl +  64) * COLS);
  float4 v2 = *(const float4*)(xp + (size_t)(bl + 128) * COLS);
  float4 v3 = *(const float4*)(xp + (size_t)(b3      ) * COLS);

  float* tp = tile + jj * TPAD;            // row jj base; rows jj+s at +s*TPAD
  const int bx0 = (bl      ) ^ jj;
  const int bx1 = (bl +  64) ^ jj;
  const int bx2 = (bl + 128) ^ jj;
  tp[0 * TPAD + bx0] = v0.x;  tp[1 * TPAD + bx0] = v0.y;
  tp[2 * TPAD + bx0] = v0.z;  tp[3 * TPAD + bx0] = v0.w;
  tp[0 * TPAD + bx1] = v1.x;  tp[1 * TPAD + bx1] = v1.y;
  tp[2 * TPAD + bx1] = v1.z;  tp[3 * TPAD + bx1] = v1.w;
  tp[0 * TPAD + bx2] = v2.x;  tp[1 * TPAD + bx2] = v2.y;
  tp[2 * TPAD + bx2] = v2.z;  tp[3 * TPAD + bx2] = v2.w;
  if (bl < 8) {
    const int bx3 = (bl + 192) ^ jj;       // in [192,224) -> fits TPAD
    tp[0 * TPAD + bx3] = v3.x;  tp[1 * TPAD + bx3] = v3.y;
    tp[2 * TPAD + bx3] = v3.z;  tp[3 * TPAD + bx3] = v3.w;
  }
  __syncthreads();
  // 32 rows x 50 float4 = 1600 aligned 16B stores, full density
#pragma unroll
  for (int q = 0; q < 4; ++q) {
    unsigned idx = (unsigned)t + ((unsigned)q << 9);
    if (idx < 1600u) {
      unsigned row = idx / 50u;            // magic-mul, unsigned
      unsigned col = (idx - row * 50u) << 2;
      unsigned cx  = col ^ (row & 28u);    // inverse swizzle, quad-contiguous
      float4 o = *(const float4*)&tile[row * TPAD + cx];
      *(float4*)(xT + (size_t)(j0 + row) * B_ + col) = o;
    }
  }
}

// ---------------- layer-1 pool + BN + ReLU + dropout (fused) ----------------
__global__ __launch_bounds__(256) void pool1_bn_kernel(
    const float* __restrict__ xT, const float* __restrict__ x,
    const int* __restrict__ src, const float* __restrict__ w,
    const float* __restrict__ bias, const int* __restrict__ rp,
    const float* __restrict__ gamma, const float* __restrict__ beta,
    float* __restrict__ out, int cpc, int use_t, uint32_t k0, uint32_t k1) {
  __shared__ float red[4][2];
  __shared__ float bcast[2];
  int b = threadIdx.x;
  int bl = b < B_ ? b : B_ - 1;
  bool valid = b < B_;
  int c0 = blockIdx.x * cpc;
  for (int cc = 0; cc < cpc; ++cc) {
    int c = c0 + cc;
    float acc = bias[c];
    int e1 = rp[c + 1];
    if (use_t) {
      for (int e = rp[c]; e < e1; ++e) {
        int s = src[e];
        const float* xp = xT + (size_t)s * (3 * B_) + bl;
        acc = fmaf(xp[0],      w[3 * e],     acc);
        acc = fmaf(xp[B_],     w[3 * e + 1], acc);
        acc = fmaf(xp[2 * B_], w[3 * e + 2], acc);
      }
    } else {
      for (int e = rp[c]; e < e1; ++e) {
        int s = src[e];
        const float* xp = x + ((size_t)bl * N0 + s) * 3;
        acc = fmaf(xp[0], w[3 * e],     acc);
        acc = fmaf(xp[1], w[3 * e + 1], acc);
        acc = fmaf(xp[2], w[3 * e + 2], acc);
      }
    }
    float sv = valid ? acc : 0.f;
    float qv = valid ? acc * acc : 0.f;
#pragma unroll
    for (int off = 32; off; off >>= 1) { sv += __shfl_xor(sv, off); qv += __shfl_xor(qv, off); }
    int wid = threadIdx.x >> 6;
    if ((threadIdx.x & 63) == 0) { red[wid][0] = sv; red[wid][1] = qv; }
    __syncthreads();
    if (threadIdx.x == 0) {
      float s2 = red[0][0] + red[1][0] + red[2][0] + red[3][0];
      float q2 = red[0][1] + red[1][1] + red[2][1] + red[3][1];
      float m   = s2 * (1.f / 200.f);
      float var = fmaf(q2, 1.f / 200.f, -m * m);
      float scale = gamma[c] * rsqrtf(var + 1e-5f);
      bcast[0] = scale;
      bcast[1] = fmaf(-m, scale, beta[c]);
    }
    __syncthreads();
    if (valid) {
      float hn = fmaxf(fmaf(acc, bcast[0], bcast[1]), 0.f);
      uint32_t idxf = (uint32_t)b * 16384u + (uint32_t)c;
      uint32_t o0, o1;
      tf2x32(k0, k1, 0u, idxf, o0, o1);
      uint32_t bits = o0 ^ o1;
      float u = __uint_as_float((bits >> 9) | 0x3f800000u) - 1.0f;
      out[(size_t)c * B_ + b] = (u < 0.9f) ? hn * (1.0f / 0.9f) : 0.0f;
    }
    __syncthreads();                       // red/bcast reused next channel
  }
}

// ---------------- layers 2..5 pool (+ optional BN/dropout), (c,b) layout ----------------
__global__ __launch_bounds__(256) void pooln_bn_kernel(
    const float* __restrict__ hin, const int* __restrict__ src,
    const float* __restrict__ w, const float* __restrict__ bias,
    const int* __restrict__ rp, const float* __restrict__ gamma,
    const float* __restrict__ beta, float* __restrict__ out,
    int cpc, int nout, int has_bn, uint32_t k0, uint32_t k1) {
  __shared__ float red[4][2];
  __shared__ float bcast[2];
  int b = threadIdx.x;
  int bl = b < B_ ? b : B_ - 1;
  bool valid = b < B_;
  int c0 = blockIdx.x * cpc;
  for (int cc = 0; cc < cpc; ++cc) {
    int c = c0 + cc;
    float acc = bias[c];
    int e1 = rp[c + 1];
    for (int e = rp[c]; e < e1; ++e)
      acc = fmaf(hin[(size_t)src[e] * B_ + bl], w[e], acc);
    if (has_bn) {
      float sv = valid ? acc : 0.f;
      float qv = valid ? acc * acc : 0.f;
#pragma unroll
      for (int off = 32; off; off >>= 1) { sv += __shfl_xor(sv, off); qv += __shfl_xor(qv, off); }
      int wid = threadIdx.x >> 6;
      if ((threadIdx.x & 63) == 0) { red[wid][0] = sv; red[wid][1] = qv; }
      __syncthreads();
      if (threadIdx.x == 0) {
        float s2 = red[0][0] + red[1][0] + red[2][0] + red[3][0];
        float q2 = red[0][1] + red[1][1] + red[2][1] + red[3][1];
        float m   = s2 * (1.f / 200.f);
        float var = fmaf(q2, 1.f / 200.f, -m * m);
        float scale = gamma[c] * rsqrtf(var + 1e-5f);
        bcast[0] = scale;
        bcast[1] = fmaf(-m, scale, beta[c]);
      }
      __syncthreads();
      if (valid) {
        float hn = fmaxf(fmaf(acc, bcast[0], bcast[1]), 0.f);
        uint32_t idxf = (uint32_t)b * (uint32_t)nout + (uint32_t)c;
        uint32_t o0, o1;
        tf2x32(k0, k1, 0u, idxf, o0, o1);
        uint32_t bits = o0 ^ o1;
        float u = __uint_as_float((bits >> 9) | 0x3f800000u) - 1.0f;
        out[(size_t)c * B_ + b] = (u < 0.9f) ? hn * (1.0f / 0.9f) : 0.0f;
      }
      __syncthreads();
    } else {
      if (valid) out[(size_t)b * 64 + c] = acc;   // final layer -> (B, 64)
    }
  }
}

// ---------------- host ----------------
extern "C" void kernel_launch(void* const* d_in, const int* in_sizes, int n_in,
                              void* d_out, int out_size, void* d_ws, size_t ws_size,
                              hipStream_t stream) {
  (void)in_sizes; (void)n_in; (void)out_size;
  const float* x = (const float*)d_in[0];
  const int*   src[5]; const int* dst[5];
  const float* w[5];   const float* bias[5];
  const float* gamma[4]; const float* beta[4];
  int idx = 1;
  for (int l = 0; l < 5; ++l) {
    src[l]  = (const int*)d_in[idx++];
    dst[l]  = (const int*)d_in[idx++];
    w[l]    = (const float*)d_in[idx++];
    bias[l] = (const float*)d_in[idx++];
    if (l < 4) { gamma[l] = (const float*)d_in[idx++]; beta[l] = (const float*)d_in[idx++]; }
  }
  static const int NOUT[5] = {16384, 4096, 1024, 256, 64};

  // dkeys = jax.random.split(key(42), 4), partitionable threefry semantics
  uint32_t dk0[4], dk1[4];
  for (uint32_t i = 0; i < 4; ++i) tf2x32(0u, 42u, 0u, i, dk0[i], dk1[i]);

  // workspace carve
  char* ws = (char*)d_ws;
  size_t off = 0;
  auto carve = [&](size_t bytes) -> void* {
    void* p = ws + off;
    off = (off + bytes + 255) & ~(size_t)255;
    return p;
  };
  int* rp[5];
  for (int l = 0; l < 5; ++l) rp[l] = (int*)carve((size_t)(NOUT[l] + 1) * sizeof(int));
  float* bufA = (float*)carve((size_t)16384 * B_ * sizeof(float));
  float* bufB = (float*)carve((size_t)16384 * B_ * sizeof(float));
  float* xT   = (float*)carve((size_t)COLS * B_ * sizeof(float));
  int use_t = (off <= ws_size) ? 1 : 0;

  float* kl = (float*)d_out + 12800;

  // 1: all row pointers + zero KL
  build_rp_all<<<(21829 + 255) / 256, 256, 0, stream>>>(
      dst[0], dst[1], dst[2], dst[3], dst[4],
      rp[0], rp[1], rp[2], rp[3], rp[4], kl);

  // 2: KL reduction (all layers)
  kl_all_kernel<<<256, 256, 0, stream>>>(w[0], w[1], w[2], w[3], w[4], kl);

  // 3: transpose (full-row tiles, XOR-swizzled LDS, branch-free loads)
  if (use_t)
    transpose_rows_kernel<<<COLS / JT, 512, 0, stream>>>(x, xT);

  // 4: layer 1 (pool + BN + ReLU + dropout)
  pool1_bn_kernel<<<16384 / 8, 256, 0, stream>>>(
      xT, x, src[0], w[0], bias[0], rp[0], gamma[0], beta[0], bufA, 8, use_t,
      dk0[0], dk1[0]);

  // 5-7: layers 2..4 (pool + BN + ReLU + dropout)
  pooln_bn_kernel<<<4096 / 4, 256, 0, stream>>>(
      bufA, src[1], w[1], bias[1], rp[1], gamma[1], beta[1], bufB, 4, 4096, 1,
      dk0[1], dk1[1]);
  pooln_bn_kernel<<<1024 / 2, 256, 0, stream>>>(
      bufB, src[2], w[2], bias[2], rp[2], gamma[2], beta[2], bufA, 2, 1024, 1,
      dk0[2], dk1[2]);
  pooln_bn_kernel<<<256, 256, 0, stream>>>(
      bufA, src[3], w[3], bias[3], rp[3], gamma[3], beta[3], bufB, 1, 256, 1,
      dk0[3], dk1[3]);

  // 8: layer 5 -> d_out (B, 64)
  pooln_bn_kernel<<<64, 256, 0, stream>>>(
      bufB, src[4], w[4], bias[4], rp[4], nullptr, nullptr, (float*)d_out, 1, 64, 0,
      0u, 0u);
}

// Round 8
// 146.842 us; speedup vs baseline: 1.2612x; 1.2597x over previous
//
#include <hip/hip_runtime.h>
#include <hip/hip_fp16.h>
#include <stdint.h>

#define B_   200
#define N0   65536
#define COLS (N0 * 3)
#define JT   32
#define TPAD 224

__device__ static inline unsigned short f2h(float f) {
  __half h = __float2half(f);              // RNE
  return *reinterpret_cast<unsigned short*>(&h);
}
__device__ static inline float h2f(unsigned short u) {
  __half h = *reinterpret_cast<__half*>(&u);
  return __half2float(h);
}

// ---------------- Threefry-2x32 (JAX-compatible, 20 rounds) ----------------
__host__ __device__ static inline void tf2x32(uint32_t k0, uint32_t k1,
                                              uint32_t x0, uint32_t x1,
                                              uint32_t& o0, uint32_t& o1) {
  const uint32_t ks2 = k0 ^ k1 ^ 0x1BD11BDAu;
  x0 += k0; x1 += k1;
#define TF_R(r) { x0 += x1; x1 = (x1 << (r)) | (x1 >> (32 - (r))); x1 ^= x0; }
  TF_R(13) TF_R(15) TF_R(26) TF_R(6)   x0 += k1;  x1 += ks2 + 1u;
  TF_R(17) TF_R(29) TF_R(16) TF_R(24)  x0 += ks2; x1 += k0  + 2u;
  TF_R(13) TF_R(15) TF_R(26) TF_R(6)   x0 += k0;  x1 += k1  + 3u;
  TF_R(17) TF_R(29) TF_R(16) TF_R(24)  x0 += k1;  x1 += ks2 + 4u;
  TF_R(13) TF_R(15) TF_R(26) TF_R(6)   x0 += ks2; x1 += k0  + 5u;
#undef TF_R
  o0 = x0; o1 = x1;
}

// ---------------- all row_ptrs in one kernel (+ zero KL slot) ----------------
__global__ void build_rp_all(const int* __restrict__ dst0, const int* __restrict__ dst1,
                             const int* __restrict__ dst2, const int* __restrict__ dst3,
                             const int* __restrict__ dst4,
                             int* rp0, int* rp1, int* rp2, int* rp3, int* rp4,
                             float* kl) {
  int tid = blockIdx.x * blockDim.x + threadIdx.x;
  if (tid == 0) *kl = 0.f;
  if (tid >= 21829) return;
  const int starts[6] = {0, 16385, 20482, 21507, 21764, 21829};
  const int EDGa[5]   = {147456, 36864, 9216, 2304, 576};
  const int* dsts[5]  = {dst0, dst1, dst2, dst3, dst4};
  int* rps[5]         = {rp0, rp1, rp2, rp3, rp4};
  int l = 0;
  while (tid >= starts[l + 1]) ++l;
  int c = tid - starts[l];
  const int* dst = dsts[l];
  int lo = 0, hi = EDGa[l];
  while (lo < hi) { int mid = (lo + hi) >> 1; if (dst[mid] < c) lo = mid + 1; else hi = mid; }
  rps[l][c] = lo;
}

// ---------------- KL over all 5 weight tensors, one kernel ----------------
__global__ __launch_bounds__(256) void kl_all_kernel(
    const float* __restrict__ w0, const float* __restrict__ w1,
    const float* __restrict__ w2, const float* __restrict__ w3,
    const float* __restrict__ w4, float* __restrict__ out) {
  __shared__ float red[256];
  const float* ws[5] = {w0, w1, w2, w3, w4};
  const int    ns[5] = {442368, 36864, 9216, 2304, 576};
  int stride = gridDim.x * blockDim.x;
  int tid0 = blockIdx.x * blockDim.x + threadIdx.x;
  float s = 0.f;
#pragma unroll
  for (int l = 0; l < 5; ++l) {
    const float* w = ws[l];
    int n = ns[l];
    for (int i = tid0; i < n; i += stride) {
      float v = w[i];
      s += fmaf(0.5f * v, v, 999.5f);      // 0.5*(w*w-1) - (-1000)
    }
  }
  red[threadIdx.x] = s;
  __syncthreads();
  for (int st = 128; st > 0; st >>= 1) {
    if (threadIdx.x < st) red[threadIdx.x] += red[threadIdx.x + st];
    __syncthreads();
  }
  if (threadIdx.x == 0) atomicAdd(out, red[0]);
}

// ---------------- transpose: 32 j-cols x ALL 200 b, fp16 output ----------------
// Read phase identical to R6 (XOR-swizzled f32 LDS tile, 4 loads in flight).
// Write phase converts to fp16: 8B per lane, rows are 400B dense.
__global__ __launch_bounds__(512, 4) void transpose_rows_kernel(
    const float* __restrict__ x, unsigned short* __restrict__ xT2) {
  __shared__ float tile[JT * TPAD];
  const int t  = threadIdx.x;              // 0..511
  const int j0 = blockIdx.x * JT;
  const int bl = t >> 3;                   // 0..63
  const int jj = (t & 7) << 2;             // 0,4,...,28

  const float* xp = x + j0 + jj;
  const int b3 = bl + 192 < B_ ? bl + 192 : B_ - 1;   // clamp, load always
  float4 v0 = *(const float4*)(xp + (size_t)(bl      ) * COLS);
  float4 v1 = *(const float4*)(xp + (size_t)(bl +  64) * COLS);
  float4 v2 = *(const float4*)(xp + (size_t)(bl + 128) * COLS);
  float4 v3 = *(const float4*)(xp + (size_t)(b3      ) * COLS);

  float* tp = tile + jj * TPAD;            // row jj base; rows jj+s at +s*TPAD
  const int bx0 = (bl      ) ^ jj;
  const int bx1 = (bl +  64) ^ jj;
  const int bx2 = (bl + 128) ^ jj;
  tp[0 * TPAD + bx0] = v0.x;  tp[1 * TPAD + bx0] = v0.y;
  tp[2 * TPAD + bx0] = v0.z;  tp[3 * TPAD + bx0] = v0.w;
  tp[0 * TPAD + bx1] = v1.x;  tp[1 * TPAD + bx1] = v1.y;
  tp[2 * TPAD + bx1] = v1.z;  tp[3 * TPAD + bx1] = v1.w;
  tp[0 * TPAD + bx2] = v2.x;  tp[1 * TPAD + bx2] = v2.y;
  tp[2 * TPAD + bx2] = v2.z;  tp[3 * TPAD + bx2] = v2.w;
  if (bl < 8) {
    const int bx3 = (bl + 192) ^ jj;       // in [192,224) -> fits TPAD
    tp[0 * TPAD + bx3] = v3.x;  tp[1 * TPAD + bx3] = v3.y;
    tp[2 * TPAD + bx3] = v3.z;  tp[3 * TPAD + bx3] = v3.w;
  }
  __syncthreads();
  // 32 rows x 50 quads = 1600 8B fp16 stores, full density (400B/row)
#pragma unroll
  for (int q = 0; q < 4; ++q) {
    unsigned idx = (unsigned)t + ((unsigned)q << 9);
    if (idx < 1600u) {
      unsigned row = idx / 50u;            // magic-mul, unsigned
      unsigned col = (idx - row * 50u) << 2;
      unsigned cx  = col ^ (row & 28u);    // inverse swizzle, quad-contiguous
      float4 o = *(const float4*)&tile[row * TPAD + cx];
      uint2 p;
      p.x = (unsigned)f2h(o.x) | ((unsigned)f2h(o.y) << 16);
      p.y = (unsigned)f2h(o.z) | ((unsigned)f2h(o.w) << 16);
      *(uint2*)(xT2 + (size_t)(j0 + row) * B_ + col) = p;
    }
  }
}

// ---------------- layer-1 pool + BN + ReLU + dropout (fused) ----------------
__global__ __launch_bounds__(256) void pool1_bn_kernel(
    const unsigned short* __restrict__ xT2, const float* __restrict__ x,
    const int* __restrict__ src, const float* __restrict__ w,
    const float* __restrict__ bias, const int* __restrict__ rp,
    const float* __restrict__ gamma, const float* __restrict__ beta,
    float* __restrict__ out, int cpc, int use_t, uint32_t k0, uint32_t k1) {
  __shared__ float red[4][2];
  __shared__ float bcast[2];
  int b = threadIdx.x;
  int bl = b < B_ ? b : B_ - 1;
  bool valid = b < B_;
  int c0 = blockIdx.x * cpc;
  for (int cc = 0; cc < cpc; ++cc) {
    int c = c0 + cc;
    float acc = bias[c];
    int e1 = rp[c + 1];
    if (use_t) {
      for (int e = rp[c]; e < e1; ++e) {
        int s = src[e];
        const unsigned short* xp = xT2 + (size_t)s * (3 * B_) + bl;
        acc = fmaf(h2f(xp[0]),      w[3 * e],     acc);
        acc = fmaf(h2f(xp[B_]),     w[3 * e + 1], acc);
        acc = fmaf(h2f(xp[2 * B_]), w[3 * e + 2], acc);
      }
    } else {
      for (int e = rp[c]; e < e1; ++e) {
        int s = src[e];
        const float* xp = x + ((size_t)bl * N0 + s) * 3;
        acc = fmaf(xp[0], w[3 * e],     acc);
        acc = fmaf(xp[1], w[3 * e + 1], acc);
        acc = fmaf(xp[2], w[3 * e + 2], acc);
      }
    }
    float sv = valid ? acc : 0.f;
    float qv = valid ? acc * acc : 0.f;
#pragma unroll
    for (int off = 32; off; off >>= 1) { sv += __shfl_xor(sv, off); qv += __shfl_xor(qv, off); }
    int wid = threadIdx.x >> 6;
    if ((threadIdx.x & 63) == 0) { red[wid][0] = sv; red[wid][1] = qv; }
    __syncthreads();
    if (threadIdx.x == 0) {
      float s2 = red[0][0] + red[1][0] + red[2][0] + red[3][0];
      float q2 = red[0][1] + red[1][1] + red[2][1] + red[3][1];
      float m   = s2 * (1.f / 200.f);
      float var = fmaf(q2, 1.f / 200.f, -m * m);
      float scale = gamma[c] * rsqrtf(var + 1e-5f);
      bcast[0] = scale;
      bcast[1] = fmaf(-m, scale, beta[c]);
    }
    __syncthreads();
    if (valid) {
      float hn = fmaxf(fmaf(acc, bcast[0], bcast[1]), 0.f);
      uint32_t idxf = (uint32_t)b * 16384u + (uint32_t)c;
      uint32_t o0, o1;
      tf2x32(k0, k1, 0u, idxf, o0, o1);
      uint32_t bits = o0 ^ o1;
      float u = __uint_as_float((bits >> 9) | 0x3f800000u) - 1.0f;
      out[(size_t)c * B_ + b] = (u < 0.9f) ? hn * (1.0f / 0.9f) : 0.0f;
    }
    __syncthreads();                       // red/bcast reused next channel
  }
}

// ---------------- layers 2..5 pool (+ optional BN/dropout), (c,b) layout ----------------
__global__ __launch_bounds__(256) void pooln_bn_kernel(
    const float* __restrict__ hin, const int* __restrict__ src,
    const float* __restrict__ w, const float* __restrict__ bias,
    const int* __restrict__ rp, const float* __restrict__ gamma,
    const float* __restrict__ beta, float* __restrict__ out,
    int cpc, int nout, int has_bn, uint32_t k0, uint32_t k1) {
  __shared__ float red[4][2];
  __shared__ float bcast[2];
  int b = threadIdx.x;
  int bl = b < B_ ? b : B_ - 1;
  bool valid = b < B_;
  int c0 = blockIdx.x * cpc;
  for (int cc = 0; cc < cpc; ++cc) {
    int c = c0 + cc;
    float acc = bias[c];
    int e1 = rp[c + 1];
    for (int e = rp[c]; e < e1; ++e)
      acc = fmaf(hin[(size_t)src[e] * B_ + bl], w[e], acc);
    if (has_bn) {
      float sv = valid ? acc : 0.f;
      float qv = valid ? acc * acc : 0.f;
#pragma unroll
      for (int off = 32; off; off >>= 1) { sv += __shfl_xor(sv, off); qv += __shfl_xor(qv, off); }
      int wid = threadIdx.x >> 6;
      if ((threadIdx.x & 63) == 0) { red[wid][0] = sv; red[wid][1] = qv; }
      __syncthreads();
      if (threadIdx.x == 0) {
        float s2 = red[0][0] + red[1][0] + red[2][0] + red[3][0];
        float q2 = red[0][1] + red[1][1] + red[2][1] + red[3][1];
        float m   = s2 * (1.f / 200.f);
        float var = fmaf(q2, 1.f / 200.f, -m * m);
        float scale = gamma[c] * rsqrtf(var + 1e-5f);
        bcast[0] = scale;
        bcast[1] = fmaf(-m, scale, beta[c]);
      }
      __syncthreads();
      if (valid) {
        float hn = fmaxf(fmaf(acc, bcast[0], bcast[1]), 0.f);
        uint32_t idxf = (uint32_t)b * (uint32_t)nout + (uint32_t)c;
        uint32_t o0, o1;
        tf2x32(k0, k1, 0u, idxf, o0, o1);
        uint32_t bits = o0 ^ o1;
        float u = __uint_as_float((bits >> 9) | 0x3f800000u) - 1.0f;
        out[(size_t)c * B_ + b] = (u < 0.9f) ? hn * (1.0f / 0.9f) : 0.0f;
      }
      __syncthreads();
    } else {
      if (valid) out[(size_t)b * 64 + c] = acc;   // final layer -> (B, 64)
    }
  }
}

// ---------------- host ----------------
extern "C" void kernel_launch(void* const* d_in, const int* in_sizes, int n_in,
                              void* d_out, int out_size, void* d_ws, size_t ws_size,
                              hipStream_t stream) {
  (void)in_sizes; (void)n_in; (void)out_size;
  const float* x = (const float*)d_in[0];
  const int*   src[5]; const int* dst[5];
  const float* w[5];   const float* bias[5];
  const float* gamma[4]; const float* beta[4];
  int idx = 1;
  for (int l = 0; l < 5; ++l) {
    src[l]  = (const int*)d_in[idx++];
    dst[l]  = (const int*)d_in[idx++];
    w[l]    = (const float*)d_in[idx++];
    bias[l] = (const float*)d_in[idx++];
    if (l < 4) { gamma[l] = (const float*)d_in[idx++]; beta[l] = (const float*)d_in[idx++]; }
  }
  static const int NOUT[5] = {16384, 4096, 1024, 256, 64};

  // dkeys = jax.random.split(key(42), 4), partitionable threefry semantics
  uint32_t dk0[4], dk1[4];
  for (uint32_t i = 0; i < 4; ++i) tf2x32(0u, 42u, 0u, i, dk0[i], dk1[i]);

  // workspace carve
  char* ws = (char*)d_ws;
  size_t off = 0;
  auto carve = [&](size_t bytes) -> void* {
    void* p = ws + off;
    off = (off + bytes + 255) & ~(size_t)255;
    return p;
  };
  int* rp[5];
  for (int l = 0; l < 5; ++l) rp[l] = (int*)carve((size_t)(NOUT[l] + 1) * sizeof(int));
  float* bufA = (float*)carve((size_t)16384 * B_ * sizeof(float));
  float* bufB = (float*)carve((size_t)16384 * B_ * sizeof(float));
  unsigned short* xT2 = (unsigned short*)carve((size_t)COLS * B_ * sizeof(unsigned short));
  int use_t = (off <= ws_size) ? 1 : 0;

  float* kl = (float*)d_out + 12800;

  // 1: all row pointers + zero KL
  build_rp_all<<<(21829 + 255) / 256, 256, 0, stream>>>(
      dst[0], dst[1], dst[2], dst[3], dst[4],
      rp[0], rp[1], rp[2], rp[3], rp[4], kl);

  // 2: KL reduction (all layers)
  kl_all_kernel<<<256, 256, 0, stream>>>(w[0], w[1], w[2], w[3], w[4], kl);

  // 3: transpose -> fp16 xT (write bytes halved; read phase unchanged)
  if (use_t)
    transpose_rows_kernel<<<COLS / JT, 512, 0, stream>>>(x, xT2);

  // 4: layer 1 (pool + BN + ReLU + dropout), fp16 gather
  pool1_bn_kernel<<<16384 / 8, 256, 0, stream>>>(
      xT2, x, src[0], w[0], bias[0], rp[0], gamma[0], beta[0], bufA, 8, use_t,
      dk0[0], dk1[0]);

  // 5-7: layers 2..4 (pool + BN + ReLU + dropout)
  pooln_bn_kernel<<<4096 / 4, 256, 0, stream>>>(
      bufA, src[1], w[1], bias[1], rp[1], gamma[1], beta[1], bufB, 4, 4096, 1,
      dk0[1], dk1[1]);
  pooln_bn_kernel<<<1024 / 2, 256, 0, stream>>>(
      bufB, src[2], w[2], bias[2], rp[2], gamma[2], beta[2], bufA, 2, 1024, 1,
      dk0[2], dk1[2]);
  pooln_bn_kernel<<<256, 256, 0, stream>>>(
      bufA, src[3], w[3], bias[3], rp[3], gamma[3], beta[3], bufB, 1, 256, 1,
      dk0[3], dk1[3]);

  // 8: layer 5 -> d_out (B, 64)
  pooln_bn_kernel<<<64, 256, 0, stream>>>(
      bufB, src[4], w[4], bias[4], rp[4], nullptr, nullptr, (float*)d_out, 1, 64, 0,
      0u, 0u);
}

// Round 9
// 146.734 us; speedup vs baseline: 1.2621x; 1.0007x over previous
//
#include <hip/hip_runtime.h>
#include <hip/hip_fp16.h>
#include <stdint.h>

#define B_    200
#define N0    65536
#define COLS  (N0 * 3)
#define JT    64
#define TPAD2 228   // ushorts; 228*2=456B row stride, 8B-aligned for uint2 reads

__device__ static inline unsigned short f2h(float f) {
  __half h = __float2half(f);              // RNE
  return *reinterpret_cast<unsigned short*>(&h);
}
__device__ static inline float h2f(unsigned short u) {
  __half h = *reinterpret_cast<__half*>(&u);
  return __half2float(h);
}

// ---------------- Threefry-2x32 (JAX-compatible, 20 rounds) ----------------
__host__ __device__ static inline void tf2x32(uint32_t k0, uint32_t k1,
                                              uint32_t x0, uint32_t x1,
                                              uint32_t& o0, uint32_t& o1) {
  const uint32_t ks2 = k0 ^ k1 ^ 0x1BD11BDAu;
  x0 += k0; x1 += k1;
#define TF_R(r) { x0 += x1; x1 = (x1 << (r)) | (x1 >> (32 - (r))); x1 ^= x0; }
  TF_R(13) TF_R(15) TF_R(26) TF_R(6)   x0 += k1;  x1 += ks2 + 1u;
  TF_R(17) TF_R(29) TF_R(16) TF_R(24)  x0 += ks2; x1 += k0  + 2u;
  TF_R(13) TF_R(15) TF_R(26) TF_R(6)   x0 += k0;  x1 += k1  + 3u;
  TF_R(17) TF_R(29) TF_R(16) TF_R(24)  x0 += k1;  x1 += ks2 + 4u;
  TF_R(13) TF_R(15) TF_R(26) TF_R(6)   x0 += ks2; x1 += k0  + 5u;
#undef TF_R
  o0 = x0; o1 = x1;
}

// ---------------- all row_ptrs in one kernel (+ zero KL slot) ----------------
__global__ void build_rp_all(const int* __restrict__ dst0, const int* __restrict__ dst1,
                             const int* __restrict__ dst2, const int* __restrict__ dst3,
                             const int* __restrict__ dst4,
                             int* rp0, int* rp1, int* rp2, int* rp3, int* rp4,
                             float* kl) {
  int tid = blockIdx.x * blockDim.x + threadIdx.x;
  if (tid == 0) *kl = 0.f;
  if (tid >= 21829) return;
  const int starts[6] = {0, 16385, 20482, 21507, 21764, 21829};
  const int EDGa[5]   = {147456, 36864, 9216, 2304, 576};
  const int* dsts[5]  = {dst0, dst1, dst2, dst3, dst4};
  int* rps[5]         = {rp0, rp1, rp2, rp3, rp4};
  int l = 0;
  while (tid >= starts[l + 1]) ++l;
  int c = tid - starts[l];
  const int* dst = dsts[l];
  int lo = 0, hi = EDGa[l];
  while (lo < hi) { int mid = (lo + hi) >> 1; if (dst[mid] < c) lo = mid + 1; else hi = mid; }
  rps[l][c] = lo;
}

// ---------------- KL over all 5 weight tensors, one kernel ----------------
__global__ __launch_bounds__(256) void kl_all_kernel(
    const float* __restrict__ w0, const float* __restrict__ w1,
    const float* __restrict__ w2, const float* __restrict__ w3,
    const float* __restrict__ w4, float* __restrict__ out) {
  __shared__ float red[256];
  const float* ws[5] = {w0, w1, w2, w3, w4};
  const int    ns[5] = {442368, 36864, 9216, 2304, 576};
  int stride = gridDim.x * blockDim.x;
  int tid0 = blockIdx.x * blockDim.x + threadIdx.x;
  float s = 0.f;
#pragma unroll
  for (int l = 0; l < 5; ++l) {
    const float* w = ws[l];
    int n = ns[l];
    for (int i = tid0; i < n; i += stride) {
      float v = w[i];
      s += fmaf(0.5f * v, v, 999.5f);      // 0.5*(w*w-1) - (-1000)
    }
  }
  red[threadIdx.x] = s;
  __syncthreads();
  for (int st = 128; st > 0; st >>= 1) {
    if (threadIdx.x < st) red[threadIdx.x] += red[threadIdx.x + st];
    __syncthreads();
  }
  if (threadIdx.x == 0) atomicAdd(out, red[0]);
}

// ---------------- transpose: 64 j-cols x ALL 200 b, fp16 LDS ----------------
// 512 threads: tx=t&15 (j-quad), bl=t>>4 (row 0..31), 7 row-passes.
// All 7 float4 loads issued BEFORE any LDS store (sched_barrier(0) fence)
// -> 7 global_load_dwordx4 in flight per lane.  256B read streak per x-row
// per block (JT=64).  LDS tile is fp16 (29KB): conversion happens pre-LDS;
// read phase is uint2 -> dense 400B xT2 rows.
__global__ __launch_bounds__(512, 4) void transpose_rows_kernel(
    const float* __restrict__ x, unsigned short* __restrict__ xT2) {
  __shared__ unsigned short tile[JT * TPAD2];
  const int t  = threadIdx.x;              // 0..511
  const int j0 = blockIdx.x * JT;
  const int tx = t & 15;                   // j-quad: cols 4tx..4tx+3
  const int bl = t >> 4;                   // 0..31

  const float* xp = x + j0 + (tx << 2);
  float4 v[7];
#pragma unroll
  for (int p = 0; p < 7; ++p) {
    int b = bl + (p << 5);
    b = b < B_ ? b : B_ - 1;               // clamp (only pass 6 clamps)
    v[p] = *(const float4*)(xp + (size_t)b * COLS);
  }
  __builtin_amdgcn_sched_barrier(0);       // loads stay ABOVE all LDS stores
#pragma unroll
  for (int p = 0; p < 7; ++p) {
    int b = bl + (p << 5);
    if (b < B_) {                          // compile-time true for p<6
      int base = (tx << 2) * TPAD2 + b;
      tile[base            ] = f2h(v[p].x);
      tile[base +     TPAD2] = f2h(v[p].y);
      tile[base + 2 * TPAD2] = f2h(v[p].z);
      tile[base + 3 * TPAD2] = f2h(v[p].w);
    }
  }
  __syncthreads();
  // 64 rows x 50 uint2 (8B = 4 fp16) = 3200 stores, dense 400B rows
#pragma unroll
  for (int q = 0; q < 7; ++q) {
    unsigned idx = (unsigned)t + ((unsigned)q << 9);
    if (idx < 3200u) {
      unsigned row = idx / 50u;            // magic-mul, unsigned
      unsigned g   = idx - row * 50u;
      uint2 o = *(const uint2*)&tile[row * TPAD2 + (g << 2)];
      *(uint2*)(xT2 + (size_t)(j0 + row) * B_ + (g << 2)) = o;
    }
  }
}

// ---------------- layer-1 pool + BN + ReLU + dropout (fused) ----------------
__global__ __launch_bounds__(256) void pool1_bn_kernel(
    const unsigned short* __restrict__ xT2, const float* __restrict__ x,
    const int* __restrict__ src, const float* __restrict__ w,
    const float* __restrict__ bias, const int* __restrict__ rp,
    const float* __restrict__ gamma, const float* __restrict__ beta,
    float* __restrict__ out, int cpc, int use_t, uint32_t k0, uint32_t k1) {
  __shared__ float red[4][2];
  __shared__ float bcast[2];
  int b = threadIdx.x;
  int bl = b < B_ ? b : B_ - 1;
  bool valid = b < B_;
  int c0 = blockIdx.x * cpc;
  for (int cc = 0; cc < cpc; ++cc) {
    int c = c0 + cc;
    float acc = bias[c];
    int e1 = rp[c + 1];
    if (use_t) {
      for (int e = rp[c]; e < e1; ++e) {
        int s = src[e];
        const unsigned short* xp = xT2 + (size_t)s * (3 * B_) + bl;
        acc = fmaf(h2f(xp[0]),      w[3 * e],     acc);
        acc = fmaf(h2f(xp[B_]),     w[3 * e + 1], acc);
        acc = fmaf(h2f(xp[2 * B_]), w[3 * e + 2], acc);
      }
    } else {
      for (int e = rp[c]; e < e1; ++e) {
        int s = src[e];
        const float* xp = x + ((size_t)bl * N0 + s) * 3;
        acc = fmaf(xp[0], w[3 * e],     acc);
        acc = fmaf(xp[1], w[3 * e + 1], acc);
        acc = fmaf(xp[2], w[3 * e + 2], acc);
      }
    }
    float sv = valid ? acc : 0.f;
    float qv = valid ? acc * acc : 0.f;
#pragma unroll
    for (int off = 32; off; off >>= 1) { sv += __shfl_xor(sv, off); qv += __shfl_xor(qv, off); }
    int wid = threadIdx.x >> 6;
    if ((threadIdx.x & 63) == 0) { red[wid][0] = sv; red[wid][1] = qv; }
    __syncthreads();
    if (threadIdx.x == 0) {
      float s2 = red[0][0] + red[1][0] + red[2][0] + red[3][0];
      float q2 = red[0][1] + red[1][1] + red[2][1] + red[3][1];
      float m   = s2 * (1.f / 200.f);
      float var = fmaf(q2, 1.f / 200.f, -m * m);
      float scale = gamma[c] * rsqrtf(var + 1e-5f);
      bcast[0] = scale;
      bcast[1] = fmaf(-m, scale, beta[c]);
    }
    __syncthreads();
    if (valid) {
      float hn = fmaxf(fmaf(acc, bcast[0], bcast[1]), 0.f);
      uint32_t idxf = (uint32_t)b * 16384u + (uint32_t)c;
      uint32_t o0, o1;
      tf2x32(k0, k1, 0u, idxf, o0, o1);
      uint32_t bits = o0 ^ o1;
      float u = __uint_as_float((bits >> 9) | 0x3f800000u) - 1.0f;
      out[(size_t)c * B_ + b] = (u < 0.9f) ? hn * (1.0f / 0.9f) : 0.0f;
    }
    __syncthreads();                       // red/bcast reused next channel
  }
}

// ---------------- layers 2..5 pool (+ optional BN/dropout), (c,b) layout ----------------
__global__ __launch_bounds__(256) void pooln_bn_kernel(
    const float* __restrict__ hin, const int* __restrict__ src,
    const float* __restrict__ w, const float* __restrict__ bias,
    const int* __restrict__ rp, const float* __restrict__ gamma,
    const float* __restrict__ beta, float* __restrict__ out,
    int cpc, int nout, int has_bn, uint32_t k0, uint32_t k1) {
  __shared__ float red[4][2];
  __shared__ float bcast[2];
  int b = threadIdx.x;
  int bl = b < B_ ? b : B_ - 1;
  bool valid = b < B_;
  int c0 = blockIdx.x * cpc;
  for (int cc = 0; cc < cpc; ++cc) {
    int c = c0 + cc;
    float acc = bias[c];
    int e1 = rp[c + 1];
    for (int e = rp[c]; e < e1; ++e)
      acc = fmaf(hin[(size_t)src[e] * B_ + bl], w[e], acc);
    if (has_bn) {
      float sv = valid ? acc : 0.f;
      float qv = valid ? acc * acc : 0.f;
#pragma unroll
      for (int off = 32; off; off >>= 1) { sv += __shfl_xor(sv, off); qv += __shfl_xor(qv, off); }
      int wid = threadIdx.x >> 6;
      if ((threadIdx.x & 63) == 0) { red[wid][0] = sv; red[wid][1] = qv; }
      __syncthreads();
      if (threadIdx.x == 0) {
        float s2 = red[0][0] + red[1][0] + red[2][0] + red[3][0];
        float q2 = red[0][1] + red[1][1] + red[2][1] + red[3][1];
        float m   = s2 * (1.f / 200.f);
        float var = fmaf(q2, 1.f / 200.f, -m * m);
        float scale = gamma[c] * rsqrtf(var + 1e-5f);
        bcast[0] = scale;
        bcast[1] = fmaf(-m, scale, beta[c]);
      }
      __syncthreads();
      if (valid) {
        float hn = fmaxf(fmaf(acc, bcast[0], bcast[1]), 0.f);
        uint32_t idxf = (uint32_t)b * (uint32_t)nout + (uint32_t)c;
        uint32_t o0, o1;
        tf2x32(k0, k1, 0u, idxf, o0, o1);
        uint32_t bits = o0 ^ o1;
        float u = __uint_as_float((bits >> 9) | 0x3f800000u) - 1.0f;
        out[(size_t)c * B_ + b] = (u < 0.9f) ? hn * (1.0f / 0.9f) : 0.0f;
      }
      __syncthreads();
    } else {
      if (valid) out[(size_t)b * 64 + c] = acc;   // final layer -> (B, 64)
    }
  }
}

// ---------------- host ----------------
extern "C" void kernel_launch(void* const* d_in, const int* in_sizes, int n_in,
                              void* d_out, int out_size, void* d_ws, size_t ws_size,
                              hipStream_t stream) {
  (void)in_sizes; (void)n_in; (void)out_size;
  const float* x = (const float*)d_in[0];
  const int*   src[5]; const int* dst[5];
  const float* w[5];   const float* bias[5];
  const float* gamma[4]; const float* beta[4];
  int idx = 1;
  for (int l = 0; l < 5; ++l) {
    src[l]  = (const int*)d_in[idx++];
    dst[l]  = (const int*)d_in[idx++];
    w[l]    = (const float*)d_in[idx++];
    bias[l] = (const float*)d_in[idx++];
    if (l < 4) { gamma[l] = (const float*)d_in[idx++]; beta[l] = (const float*)d_in[idx++]; }
  }
  static const int NOUT[5] = {16384, 4096, 1024, 256, 64};

  // dkeys = jax.random.split(key(42), 4), partitionable threefry semantics
  uint32_t dk0[4], dk1[4];
  for (uint32_t i = 0; i < 4; ++i) tf2x32(0u, 42u, 0u, i, dk0[i], dk1[i]);

  // workspace carve
  char* ws = (char*)d_ws;
  size_t off = 0;
  auto carve = [&](size_t bytes) -> void* {
    void* p = ws + off;
    off = (off + bytes + 255) & ~(size_t)255;
    return p;
  };
  int* rp[5];
  for (int l = 0; l < 5; ++l) rp[l] = (int*)carve((size_t)(NOUT[l] + 1) * sizeof(int));
  float* bufA = (float*)carve((size_t)16384 * B_ * sizeof(float));
  float* bufB = (float*)carve((size_t)16384 * B_ * sizeof(float));
  unsigned short* xT2 = (unsigned short*)carve((size_t)COLS * B_ * sizeof(unsigned short));
  int use_t = (off <= ws_size) ? 1 : 0;

  float* kl = (float*)d_out + 12800;

  // 1: all row pointers + zero KL
  build_rp_all<<<(21829 + 255) / 256, 256, 0, stream>>>(
      dst[0], dst[1], dst[2], dst[3], dst[4],
      rp[0], rp[1], rp[2], rp[3], rp[4], kl);

  // 2: KL reduction (all layers)
  kl_all_kernel<<<256, 256, 0, stream>>>(w[0], w[1], w[2], w[3], w[4], kl);

  // 3: transpose -> fp16 xT (JT=64, forced-MLP loads, fp16 LDS)
  if (use_t)
    transpose_rows_kernel<<<COLS / JT, 512, 0, stream>>>(x, xT2);

  // 4: layer 1 (pool + BN + ReLU + dropout), fp16 gather
  pool1_bn_kernel<<<16384 / 8, 256, 0, stream>>>(
      xT2, x, src[0], w[0], bias[0], rp[0], gamma[0], beta[0], bufA, 8, use_t,
      dk0[0], dk1[0]);

  // 5-7: layers 2..4 (pool + BN + ReLU + dropout)
  pooln_bn_kernel<<<4096 / 4, 256, 0, stream>>>(
      bufA, src[1], w[1], bias[1], rp[1], gamma[1], beta[1], bufB, 4, 4096, 1,
      dk0[1], dk1[1]);
  pooln_bn_kernel<<<1024 / 2, 256, 0, stream>>>(
      bufB, src[2], w[2], bias[2], rp[2], gamma[2], beta[2], bufA, 2, 1024, 1,
      dk0[2], dk1[2]);
  pooln_bn_kernel<<<256, 256, 0, stream>>>(
      bufA, src[3], w[3], bias[3], rp[3], gamma[3], beta[3], bufB, 1, 256, 1,
      dk0[3], dk1[3]);

  // 8: layer 5 -> d_out (B, 64)
  pooln_bn_kernel<<<64, 256, 0, stream>>>(
      bufB, src[4], w[4], bias[4], rp[4], nullptr, nullptr, (float*)d_out, 1, 64, 0,
      0u, 0u);
}

// Round 10
// 137.343 us; speedup vs baseline: 1.3484x; 1.0684x over previous
//
#include <hip/hip_runtime.h>
#include <hip/hip_fp16.h>
#include <stdint.h>

#define B_    200
#define N0    65536
#define COLS  (N0 * 3)
#define JT    64
#define TPAD2 228   // ushorts; 228*2=456B row stride, 8B-aligned for uint2 reads

__device__ static inline unsigned short f2h(float f) {
  __half h = __float2half(f);              // RNE
  return *reinterpret_cast<unsigned short*>(&h);
}
__device__ static inline float h2f(unsigned short u) {
  __half h = *reinterpret_cast<__half*>(&u);
  return __half2float(h);
}

// ---------------- Threefry-2x32 (JAX-compatible, 20 rounds) ----------------
__host__ __device__ static inline void tf2x32(uint32_t k0, uint32_t k1,
                                              uint32_t x0, uint32_t x1,
                                              uint32_t& o0, uint32_t& o1) {
  const uint32_t ks2 = k0 ^ k1 ^ 0x1BD11BDAu;
  x0 += k0; x1 += k1;
#define TF_R(r) { x0 += x1; x1 = (x1 << (r)) | (x1 >> (32 - (r))); x1 ^= x0; }
  TF_R(13) TF_R(15) TF_R(26) TF_R(6)   x0 += k1;  x1 += ks2 + 1u;
  TF_R(17) TF_R(29) TF_R(16) TF_R(24)  x0 += ks2; x1 += k0  + 2u;
  TF_R(13) TF_R(15) TF_R(26) TF_R(6)   x0 += k0;  x1 += k1  + 3u;
  TF_R(17) TF_R(29) TF_R(16) TF_R(24)  x0 += k1;  x1 += ks2 + 4u;
  TF_R(13) TF_R(15) TF_R(26) TF_R(6)   x0 += ks2; x1 += k0  + 5u;
#undef TF_R
  o0 = x0; o1 = x1;
}

__device__ static inline float drop_mask_apply(float hn, uint32_t b, uint32_t c,
                                               uint32_t nout, uint32_t k0, uint32_t k1) {
  uint32_t o0, o1;
  tf2x32(k0, k1, 0u, b * nout + c, o0, o1);
  uint32_t bits = o0 ^ o1;
  float u = __uint_as_float((bits >> 9) | 0x3f800000u) - 1.0f;
  return (u < 0.9f) ? hn * (1.0f / 0.9f) : 0.0f;
}

// ---------------- all row_ptrs in one kernel (+ zero KL slot) ----------------
__global__ void build_rp_all(const int* __restrict__ dst0, const int* __restrict__ dst1,
                             const int* __restrict__ dst2, const int* __restrict__ dst3,
                             const int* __restrict__ dst4,
                             int* rp0, int* rp1, int* rp2, int* rp3, int* rp4,
                             float* kl) {
  int tid = blockIdx.x * blockDim.x + threadIdx.x;
  if (tid == 0) *kl = 0.f;
  if (tid >= 21829) return;
  const int starts[6] = {0, 16385, 20482, 21507, 21764, 21829};
  const int EDGa[5]   = {147456, 36864, 9216, 2304, 576};
  const int* dsts[5]  = {dst0, dst1, dst2, dst3, dst4};
  int* rps[5]         = {rp0, rp1, rp2, rp3, rp4};
  int l = 0;
  while (tid >= starts[l + 1]) ++l;
  int c = tid - starts[l];
  const int* dst = dsts[l];
  int lo = 0, hi = EDGa[l];
  while (lo < hi) { int mid = (lo + hi) >> 1; if (dst[mid] < c) lo = mid + 1; else hi = mid; }
  rps[l][c] = lo;
}

// ---------------- KL over all 5 weight tensors, one kernel ----------------
__global__ __launch_bounds__(256) void kl_all_kernel(
    const float* __restrict__ w0, const float* __restrict__ w1,
    const float* __restrict__ w2, const float* __restrict__ w3,
    const float* __restrict__ w4, float* __restrict__ out) {
  __shared__ float red[256];
  const float* ws[5] = {w0, w1, w2, w3, w4};
  const int    ns[5] = {442368, 36864, 9216, 2304, 576};
  int stride = gridDim.x * blockDim.x;
  int tid0 = blockIdx.x * blockDim.x + threadIdx.x;
  float s = 0.f;
#pragma unroll
  for (int l = 0; l < 5; ++l) {
    const float* w = ws[l];
    int n = ns[l];
    for (int i = tid0; i < n; i += stride) {
      float v = w[i];
      s += fmaf(0.5f * v, v, 999.5f);      // 0.5*(w*w-1) - (-1000)
    }
  }
  red[threadIdx.x] = s;
  __syncthreads();
  for (int st = 128; st > 0; st >>= 1) {
    if (threadIdx.x < st) red[threadIdx.x] += red[threadIdx.x + st];
    __syncthreads();
  }
  if (threadIdx.x == 0) atomicAdd(out, red[0]);
}

// ---------------- transpose: 64 j-cols x ALL 200 b, fp16 LDS ----------------
__global__ __launch_bounds__(512, 4) void transpose_rows_kernel(
    const float* __restrict__ x, unsigned short* __restrict__ xT2) {
  __shared__ unsigned short tile[JT * TPAD2];
  const int t  = threadIdx.x;              // 0..511
  const int j0 = blockIdx.x * JT;
  const int tx = t & 15;                   // j-quad: cols 4tx..4tx+3
  const int bl = t >> 4;                   // 0..31

  const float* xp = x + j0 + (tx << 2);
  float4 v[7];
#pragma unroll
  for (int p = 0; p < 7; ++p) {
    int b = bl + (p << 5);
    b = b < B_ ? b : B_ - 1;               // clamp (only pass 6 clamps)
    v[p] = *(const float4*)(xp + (size_t)b * COLS);
  }
  __builtin_amdgcn_sched_barrier(0);       // loads stay ABOVE all LDS stores
#pragma unroll
  for (int p = 0; p < 7; ++p) {
    int b = bl + (p << 5);
    if (b < B_) {                          // compile-time true for p<6
      int base = (tx << 2) * TPAD2 + b;
      tile[base            ] = f2h(v[p].x);
      tile[base +     TPAD2] = f2h(v[p].y);
      tile[base + 2 * TPAD2] = f2h(v[p].z);
      tile[base + 3 * TPAD2] = f2h(v[p].w);
    }
  }
  __syncthreads();
  // 64 rows x 50 uint2 (8B = 4 fp16) = 3200 stores, dense 400B rows
#pragma unroll
  for (int q = 0; q < 7; ++q) {
    unsigned idx = (unsigned)t + ((unsigned)q << 9);
    if (idx < 3200u) {
      unsigned row = idx / 50u;            // magic-mul, unsigned
      unsigned g   = idx - row * 50u;
      uint2 o = *(const uint2*)&tile[row * TPAD2 + (g << 2)];
      *(uint2*)(xT2 + (size_t)(j0 + row) * B_ + (g << 2)) = o;
    }
  }
}

// ---------------- layer-1 pool + BN + ReLU + dropout: WAVE PER CHANNEL ----------------
// 64 lanes own channel c; lane l holds batches {2l,2l+1} and {128+2l,129+2l}
// as uint32 fp16-pairs (4B coalesced loads).  BN stats via 6-step shfl_xor
// butterfly -- NO LDS, NO __syncthreads.  4 waves/block = 4 channels/block.
__global__ __launch_bounds__(256) void pool1_bn_wave(
    const unsigned short* __restrict__ xT2, const int* __restrict__ src,
    const float* __restrict__ w, const float* __restrict__ bias,
    const int* __restrict__ rp, const float* __restrict__ gamma,
    const float* __restrict__ beta, float* __restrict__ out,
    uint32_t k0, uint32_t k1) {
  const int l   = threadIdx.x & 63;
  const int c   = (blockIdx.x << 2) + (threadIdx.x >> 6);
  const int l2  = l << 1;                        // b = l2, l2+1 (<=127)
  const bool hi = (l < 36);                      // b = 128+l2, 129+l2 valid
  const int lm2 = (hi ? l2 : 70) + 128;          // clamped hi-pair offset

  float a00 = 0.f, a01 = 0.f, a10 = 0.f, a11 = 0.f;
  const int e1 = rp[c + 1];
  for (int e = rp[c]; e < e1; ++e) {
    const unsigned short* base = xT2 + (size_t)src[e] * (3 * B_);
    float w0 = w[3 * e], w1 = w[3 * e + 1], w2 = w[3 * e + 2];
    uint32_t p0 = *(const uint32_t*)(base +           l2);
    uint32_t p1 = *(const uint32_t*)(base +     B_ +  l2);
    uint32_t p2 = *(const uint32_t*)(base + 2 * B_ +  l2);
    uint32_t q0 = *(const uint32_t*)(base +           lm2);
    uint32_t q1 = *(const uint32_t*)(base +     B_ +  lm2);
    uint32_t q2 = *(const uint32_t*)(base + 2 * B_ +  lm2);
    a00 = fmaf(h2f((unsigned short)p0), w0, a00);
    a01 = fmaf(h2f((unsigned short)(p0 >> 16)), w0, a01);
    a00 = fmaf(h2f((unsigned short)p1), w1, a00);
    a01 = fmaf(h2f((unsigned short)(p1 >> 16)), w1, a01);
    a00 = fmaf(h2f((unsigned short)p2), w2, a00);
    a01 = fmaf(h2f((unsigned short)(p2 >> 16)), w2, a01);
    a10 = fmaf(h2f((unsigned short)q0), w0, a10);
    a11 = fmaf(h2f((unsigned short)(q0 >> 16)), w0, a11);
    a10 = fmaf(h2f((unsigned short)q1), w1, a10);
    a11 = fmaf(h2f((unsigned short)(q1 >> 16)), w1, a11);
    a10 = fmaf(h2f((unsigned short)q2), w2, a10);
    a11 = fmaf(h2f((unsigned short)(q2 >> 16)), w2, a11);
  }
  const float bi = bias[c];
  a00 += bi; a01 += bi; a10 += bi; a11 += bi;

  float sv = a00 + a01 + (hi ? a10 + a11 : 0.f);
  float qv = a00 * a00 + a01 * a01 + (hi ? a10 * a10 + a11 * a11 : 0.f);
#pragma unroll
  for (int off = 32; off; off >>= 1) {
    sv += __shfl_xor(sv, off);
    qv += __shfl_xor(qv, off);
  }
  const float m   = sv * (1.f / 200.f);
  const float var = fmaf(qv, 1.f / 200.f, -m * m);
  const float scale = gamma[c] * rsqrtf(var + 1e-5f);
  const float shift = fmaf(-m, scale, beta[c]);

  float2 r0;
  r0.x = drop_mask_apply(fmaxf(fmaf(a00, scale, shift), 0.f), (uint32_t)l2,       (uint32_t)c, 16384u, k0, k1);
  r0.y = drop_mask_apply(fmaxf(fmaf(a01, scale, shift), 0.f), (uint32_t)l2 + 1u,  (uint32_t)c, 16384u, k0, k1);
  *(float2*)(out + (size_t)c * B_ + l2) = r0;
  if (hi) {
    float2 r1;
    r1.x = drop_mask_apply(fmaxf(fmaf(a10, scale, shift), 0.f), (uint32_t)(128 + l2), (uint32_t)c, 16384u, k0, k1);
    r1.y = drop_mask_apply(fmaxf(fmaf(a11, scale, shift), 0.f), (uint32_t)(129 + l2), (uint32_t)c, 16384u, k0, k1);
    *(float2*)(out + (size_t)c * B_ + 128 + l2) = r1;
  }
}

// ---------------- layers 2..5 pool (+ optional BN/dropout), (c,b) layout ----------------
__global__ __launch_bounds__(256) void pooln_bn_kernel(
    const float* __restrict__ hin, const int* __restrict__ src,
    const float* __restrict__ w, const float* __restrict__ bias,
    const int* __restrict__ rp, const float* __restrict__ gamma,
    const float* __restrict__ beta, float* __restrict__ out,
    int cpc, int nout, int has_bn, uint32_t k0, uint32_t k1) {
  __shared__ float red[4][2];
  __shared__ float bcast[2];
  int b = threadIdx.x;
  int bl = b < B_ ? b : B_ - 1;
  bool valid = b < B_;
  int c0 = blockIdx.x * cpc;
  for (int cc = 0; cc < cpc; ++cc) {
    int c = c0 + cc;
    float acc = bias[c];
    int e1 = rp[c + 1];
    for (int e = rp[c]; e < e1; ++e)
      acc = fmaf(hin[(size_t)src[e] * B_ + bl], w[e], acc);
    if (has_bn) {
      float sv = valid ? acc : 0.f;
      float qv = valid ? acc * acc : 0.f;
#pragma unroll
      for (int off = 32; off; off >>= 1) { sv += __shfl_xor(sv, off); qv += __shfl_xor(qv, off); }
      int wid = threadIdx.x >> 6;
      if ((threadIdx.x & 63) == 0) { red[wid][0] = sv; red[wid][1] = qv; }
      __syncthreads();
      if (threadIdx.x == 0) {
        float s2 = red[0][0] + red[1][0] + red[2][0] + red[3][0];
        float q2 = red[0][1] + red[1][1] + red[2][1] + red[3][1];
        float m   = s2 * (1.f / 200.f);
        float var = fmaf(q2, 1.f / 200.f, -m * m);
        float scale = gamma[c] * rsqrtf(var + 1e-5f);
        bcast[0] = scale;
        bcast[1] = fmaf(-m, scale, beta[c]);
      }
      __syncthreads();
      if (valid) {
        float hn = fmaxf(fmaf(acc, bcast[0], bcast[1]), 0.f);
        out[(size_t)c * B_ + b] =
            drop_mask_apply(hn, (uint32_t)b, (uint32_t)c, (uint32_t)nout, k0, k1);
      }
      __syncthreads();
    } else {
      if (valid) out[(size_t)b * 64 + c] = acc;   // final layer -> (B, 64)
    }
  }
}

// ---------------- host ----------------
extern "C" void kernel_launch(void* const* d_in, const int* in_sizes, int n_in,
                              void* d_out, int out_size, void* d_ws, size_t ws_size,
                              hipStream_t stream) {
  (void)in_sizes; (void)n_in; (void)out_size;
  const float* x = (const float*)d_in[0];
  const int*   src[5]; const int* dst[5];
  const float* w[5];   const float* bias[5];
  const float* gamma[4]; const float* beta[4];
  int idx = 1;
  for (int l = 0; l < 5; ++l) {
    src[l]  = (const int*)d_in[idx++];
    dst[l]  = (const int*)d_in[idx++];
    w[l]    = (const float*)d_in[idx++];
    bias[l] = (const float*)d_in[idx++];
    if (l < 4) { gamma[l] = (const float*)d_in[idx++]; beta[l] = (const float*)d_in[idx++]; }
  }
  static const int NOUT[5] = {16384, 4096, 1024, 256, 64};

  // dkeys = jax.random.split(key(42), 4), partitionable threefry semantics
  uint32_t dk0[4], dk1[4];
  for (uint32_t i = 0; i < 4; ++i) tf2x32(0u, 42u, 0u, i, dk0[i], dk1[i]);

  // workspace carve
  char* ws = (char*)d_ws;
  size_t off = 0;
  auto carve = [&](size_t bytes) -> void* {
    void* p = ws + off;
    off = (off + bytes + 255) & ~(size_t)255;
    return p;
  };
  int* rp[5];
  for (int l = 0; l < 5; ++l) rp[l] = (int*)carve((size_t)(NOUT[l] + 1) * sizeof(int));
  float* bufA = (float*)carve((size_t)16384 * B_ * sizeof(float));
  float* bufB = (float*)carve((size_t)16384 * B_ * sizeof(float));
  unsigned short* xT2 = (unsigned short*)carve((size_t)COLS * B_ * sizeof(unsigned short));
  (void)ws_size;

  float* kl = (float*)d_out + 12800;

  // 1: all row pointers + zero KL
  build_rp_all<<<(21829 + 255) / 256, 256, 0, stream>>>(
      dst[0], dst[1], dst[2], dst[3], dst[4],
      rp[0], rp[1], rp[2], rp[3], rp[4], kl);

  // 2: KL reduction (all layers)
  kl_all_kernel<<<256, 256, 0, stream>>>(w[0], w[1], w[2], w[3], w[4], kl);

  // 3: transpose -> fp16 xT
  transpose_rows_kernel<<<COLS / JT, 512, 0, stream>>>(x, xT2);

  // 4: layer 1 — wave-per-channel, no barriers
  pool1_bn_wave<<<16384 / 4, 256, 0, stream>>>(
      xT2, src[0], w[0], bias[0], rp[0], gamma[0], beta[0], bufA,
      dk0[0], dk1[0]);

  // 5-7: layers 2..4 (pool + BN + ReLU + dropout)
  pooln_bn_kernel<<<4096 / 4, 256, 0, stream>>>(
      bufA, src[1], w[1], bias[1], rp[1], gamma[1], beta[1], bufB, 4, 4096, 1,
      dk0[1], dk1[1]);
  pooln_bn_kernel<<<1024 / 2, 256, 0, stream>>>(
      bufB, src[2], w[2], bias[2], rp[2], gamma[2], beta[2], bufA, 2, 1024, 1,
      dk0[2], dk1[2]);
  pooln_bn_kernel<<<256, 256, 0, stream>>>(
      bufA, src[3], w[3], bias[3], rp[3], gamma[3], beta[3], bufB, 1, 256, 1,
      dk0[3], dk1[3]);

  // 8: layer 5 -> d_out (B, 64)
  pooln_bn_kernel<<<64, 256, 0, stream>>>(
      bufB, src[4], w[4], bias[4], rp[4], nullptr, nullptr, (float*)d_out, 1, 64, 0,
      0u, 0u);
}

// Round 11
// 114.334 us; speedup vs baseline: 1.6198x; 1.2012x over previous
//
#include <hip/hip_runtime.h>
#include <hip/hip_fp16.h>
#include <stdint.h>

#define B_    200
#define N0    65536
#define COLS  (N0 * 3)
#define JT    64
#define TPAD2 228   // ushorts; 228*2=456B row stride, 8B-aligned for uint2 reads

__device__ static inline unsigned short f2h(float f) {
  __half h = __float2half(f);              // RNE
  return *reinterpret_cast<unsigned short*>(&h);
}
__device__ static inline float h2f(unsigned short u) {
  __half h = *reinterpret_cast<__half*>(&u);
  return __half2float(h);
}

// ---------------- Threefry-2x32 (JAX-compatible, 20 rounds) ----------------
__host__ __device__ static inline void tf2x32(uint32_t k0, uint32_t k1,
                                              uint32_t x0, uint32_t x1,
                                              uint32_t& o0, uint32_t& o1) {
  const uint32_t ks2 = k0 ^ k1 ^ 0x1BD11BDAu;
  x0 += k0; x1 += k1;
#define TF_R(r) { x0 += x1; x1 = (x1 << (r)) | (x1 >> (32 - (r))); x1 ^= x0; }
  TF_R(13) TF_R(15) TF_R(26) TF_R(6)   x0 += k1;  x1 += ks2 + 1u;
  TF_R(17) TF_R(29) TF_R(16) TF_R(24)  x0 += ks2; x1 += k0  + 2u;
  TF_R(13) TF_R(15) TF_R(26) TF_R(6)   x0 += k0;  x1 += k1  + 3u;
  TF_R(17) TF_R(29) TF_R(16) TF_R(24)  x0 += k1;  x1 += ks2 + 4u;
  TF_R(13) TF_R(15) TF_R(26) TF_R(6)   x0 += ks2; x1 += k0  + 5u;
#undef TF_R
  o0 = x0; o1 = x1;
}

__device__ static inline float drop_mask_apply(float hn, uint32_t b, uint32_t c,
                                               uint32_t nout, uint32_t k0, uint32_t k1) {
  uint32_t o0, o1;
  tf2x32(k0, k1, 0u, b * nout + c, o0, o1);
  uint32_t bits = o0 ^ o1;
  float u = __uint_as_float((bits >> 9) | 0x3f800000u) - 1.0f;
  return (u < 0.9f) ? hn * (1.0f / 0.9f) : 0.0f;
}

// ---------------- all row_ptrs in one kernel (+ zero KL slot) ----------------
__global__ void build_rp_all(const int* __restrict__ dst0, const int* __restrict__ dst1,
                             const int* __restrict__ dst2, const int* __restrict__ dst3,
                             const int* __restrict__ dst4,
                             int* rp0, int* rp1, int* rp2, int* rp3, int* rp4,
                             float* kl) {
  int tid = blockIdx.x * blockDim.x + threadIdx.x;
  if (tid == 0) *kl = 0.f;
  if (tid >= 21829) return;
  const int starts[6] = {0, 16385, 20482, 21507, 21764, 21829};
  const int EDGa[5]   = {147456, 36864, 9216, 2304, 576};
  const int* dsts[5]  = {dst0, dst1, dst2, dst3, dst4};
  int* rps[5]         = {rp0, rp1, rp2, rp3, rp4};
  int l = 0;
  while (tid >= starts[l + 1]) ++l;
  int c = tid - starts[l];
  const int* dst = dsts[l];
  int lo = 0, hi = EDGa[l];
  while (lo < hi) { int mid = (lo + hi) >> 1; if (dst[mid] < c) lo = mid + 1; else hi = mid; }
  rps[l][c] = lo;
}

// ---------------- KL over all 5 weight tensors, one kernel ----------------
__global__ __launch_bounds__(256) void kl_all_kernel(
    const float* __restrict__ w0, const float* __restrict__ w1,
    const float* __restrict__ w2, const float* __restrict__ w3,
    const float* __restrict__ w4, float* __restrict__ out) {
  __shared__ float red[256];
  const float* ws[5] = {w0, w1, w2, w3, w4};
  const int    ns[5] = {442368, 36864, 9216, 2304, 576};
  int stride = gridDim.x * blockDim.x;
  int tid0 = blockIdx.x * blockDim.x + threadIdx.x;
  float s = 0.f;
#pragma unroll
  for (int l = 0; l < 5; ++l) {
    const float* w = ws[l];
    int n = ns[l];
    for (int i = tid0; i < n; i += stride) {
      float v = w[i];
      s += fmaf(0.5f * v, v, 999.5f);      // 0.5*(w*w-1) - (-1000)
    }
  }
  red[threadIdx.x] = s;
  __syncthreads();
  for (int st = 128; st > 0; st >>= 1) {
    if (threadIdx.x < st) red[threadIdx.x] += red[threadIdx.x + st];
    __syncthreads();
  }
  if (threadIdx.x == 0) atomicAdd(out, red[0]);
}

// ---------------- transpose: 64 j-cols x ALL 200 b, fp16 LDS ----------------
__global__ __launch_bounds__(512, 4) void transpose_rows_kernel(
    const float* __restrict__ x, unsigned short* __restrict__ xT2) {
  __shared__ unsigned short tile[JT * TPAD2];
  const int t  = threadIdx.x;              // 0..511
  const int j0 = blockIdx.x * JT;
  const int tx = t & 15;                   // j-quad: cols 4tx..4tx+3
  const int bl = t >> 4;                   // 0..31

  const float* xp = x + j0 + (tx << 2);
  float4 v[7];
#pragma unroll
  for (int p = 0; p < 7; ++p) {
    int b = bl + (p << 5);
    b = b < B_ ? b : B_ - 1;               // clamp (only pass 6 clamps)
    v[p] = *(const float4*)(xp + (size_t)b * COLS);
  }
  __builtin_amdgcn_sched_barrier(0);       // loads stay ABOVE all LDS stores
#pragma unroll
  for (int p = 0; p < 7; ++p) {
    int b = bl + (p << 5);
    if (b < B_) {                          // compile-time true for p<6
      int base = (tx << 2) * TPAD2 + b;
      tile[base            ] = f2h(v[p].x);
      tile[base +     TPAD2] = f2h(v[p].y);
      tile[base + 2 * TPAD2] = f2h(v[p].z);
      tile[base + 3 * TPAD2] = f2h(v[p].w);
    }
  }
  __syncthreads();
  // 64 rows x 50 uint2 (8B = 4 fp16) = 3200 stores, dense 400B rows
#pragma unroll
  for (int q = 0; q < 7; ++q) {
    unsigned idx = (unsigned)t + ((unsigned)q << 9);
    if (idx < 3200u) {
      unsigned row = idx / 50u;            // magic-mul, unsigned
      unsigned g   = idx - row * 50u;
      uint2 o = *(const uint2*)&tile[row * TPAD2 + (g << 2)];
      *(uint2*)(xT2 + (size_t)(j0 + row) * B_ + (g << 2)) = o;
    }
  }
}

// ---------------- layer-1 pool + BN + ReLU + dropout: WAVE PER CHANNEL ----------------
// Output packed fp16 pairs.  Edge loop unrolled x2 for MLP.
__global__ __launch_bounds__(256) void pool1_bn_wave(
    const unsigned short* __restrict__ xT2, const int* __restrict__ src,
    const float* __restrict__ w, const float* __restrict__ bias,
    const int* __restrict__ rp, const float* __restrict__ gamma,
    const float* __restrict__ beta, unsigned short* __restrict__ out,
    uint32_t k0, uint32_t k1) {
  const int l   = threadIdx.x & 63;
  const int c   = (blockIdx.x << 2) + (threadIdx.x >> 6);
  const int l2  = l << 1;                        // b = l2, l2+1 (<=127)
  const bool hi = (l < 36);                      // b = 128+l2, 129+l2 valid
  const int lm2 = (hi ? l2 : 70) + 128;          // clamped hi-pair offset

  float a00 = 0.f, a01 = 0.f, a10 = 0.f, a11 = 0.f;
  const int e0 = rp[c], e1 = rp[c + 1];
  int e = e0;
#define P1_EDGE(EE)                                                          \
  {                                                                          \
    const unsigned short* base = xT2 + (size_t)src[EE] * (3 * B_);           \
    float w0 = w[3 * (EE)], w1 = w[3 * (EE) + 1], w2 = w[3 * (EE) + 2];      \
    uint32_t p0 = *(const uint32_t*)(base +           l2);                   \
    uint32_t p1 = *(const uint32_t*)(base +     B_ +  l2);                   \
    uint32_t p2 = *(const uint32_t*)(base + 2 * B_ +  l2);                   \
    uint32_t q0 = *(const uint32_t*)(base +           lm2);                  \
    uint32_t q1 = *(const uint32_t*)(base +     B_ +  lm2);                  \
    uint32_t q2 = *(const uint32_t*)(base + 2 * B_ +  lm2);                  \
    a00 = fmaf(h2f((unsigned short)p0), w0, a00);                            \
    a01 = fmaf(h2f((unsigned short)(p0 >> 16)), w0, a01);                    \
    a00 = fmaf(h2f((unsigned short)p1), w1, a00);                            \
    a01 = fmaf(h2f((unsigned short)(p1 >> 16)), w1, a01);                    \
    a00 = fmaf(h2f((unsigned short)p2), w2, a00);                            \
    a01 = fmaf(h2f((unsigned short)(p2 >> 16)), w2, a01);                    \
    a10 = fmaf(h2f((unsigned short)q0), w0, a10);                            \
    a11 = fmaf(h2f((unsigned short)(q0 >> 16)), w0, a11);                    \
    a10 = fmaf(h2f((unsigned short)q1), w1, a10);                            \
    a11 = fmaf(h2f((unsigned short)(q1 >> 16)), w1, a11);                    \
    a10 = fmaf(h2f((unsigned short)q2), w2, a10);                            \
    a11 = fmaf(h2f((unsigned short)(q2 >> 16)), w2, a11);                    \
  }
  for (; e + 2 <= e1; e += 2) { P1_EDGE(e) P1_EDGE(e + 1) }
  for (; e < e1; ++e) { P1_EDGE(e) }
#undef P1_EDGE
  const float bi = bias[c];
  a00 += bi; a01 += bi; a10 += bi; a11 += bi;

  float sv = a00 + a01 + (hi ? a10 + a11 : 0.f);
  float qv = a00 * a00 + a01 * a01 + (hi ? a10 * a10 + a11 * a11 : 0.f);
#pragma unroll
  for (int off = 32; off; off >>= 1) {
    sv += __shfl_xor(sv, off);
    qv += __shfl_xor(qv, off);
  }
  const float m   = sv * (1.f / 200.f);
  const float var = fmaf(qv, 1.f / 200.f, -m * m);
  const float scale = gamma[c] * rsqrtf(var + 1e-5f);
  const float shift = fmaf(-m, scale, beta[c]);

  float r0 = drop_mask_apply(fmaxf(fmaf(a00, scale, shift), 0.f), (uint32_t)l2,      (uint32_t)c, 16384u, k0, k1);
  float r1 = drop_mask_apply(fmaxf(fmaf(a01, scale, shift), 0.f), (uint32_t)l2 + 1u, (uint32_t)c, 16384u, k0, k1);
  *(uint32_t*)(out + (size_t)c * B_ + l2) = (uint32_t)f2h(r0) | ((uint32_t)f2h(r1) << 16);
  if (hi) {
    float r2 = drop_mask_apply(fmaxf(fmaf(a10, scale, shift), 0.f), (uint32_t)(128 + l2), (uint32_t)c, 16384u, k0, k1);
    float r3 = drop_mask_apply(fmaxf(fmaf(a11, scale, shift), 0.f), (uint32_t)(129 + l2), (uint32_t)c, 16384u, k0, k1);
    *(uint32_t*)(out + (size_t)c * B_ + 128 + l2) = (uint32_t)f2h(r2) | ((uint32_t)f2h(r3) << 16);
  }
}

// ---------------- layers 2..5: WAVE PER CHANNEL, fp16 in ----------------
// din=1.  has_bn: BN+ReLU+dropout -> fp16 (c,b).  else: +bias -> f32 (B,64).
__global__ __launch_bounds__(256) void pooln_wave(
    const unsigned short* __restrict__ hin, const int* __restrict__ src,
    const float* __restrict__ w, const float* __restrict__ bias,
    const int* __restrict__ rp, const float* __restrict__ gamma,
    const float* __restrict__ beta, void* __restrict__ outv,
    int nout, int has_bn, uint32_t k0, uint32_t k1) {
  const int l   = threadIdx.x & 63;
  const int c   = (blockIdx.x << 2) + (threadIdx.x >> 6);
  const int l2  = l << 1;
  const bool hi = (l < 36);
  const int lm2 = (hi ? l2 : 70) + 128;

  float a00 = 0.f, a01 = 0.f, a10 = 0.f, a11 = 0.f;
  const int e0 = rp[c], e1 = rp[c + 1];
  int e = e0;
#define PN_EDGE(EE)                                                          \
  {                                                                          \
    const unsigned short* base = hin + (size_t)src[EE] * B_;                 \
    float we = w[EE];                                                        \
    uint32_t p0 = *(const uint32_t*)(base + l2);                             \
    uint32_t q0 = *(const uint32_t*)(base + lm2);                            \
    a00 = fmaf(h2f((unsigned short)p0), we, a00);                            \
    a01 = fmaf(h2f((unsigned short)(p0 >> 16)), we, a01);                    \
    a10 = fmaf(h2f((unsigned short)q0), we, a10);                            \
    a11 = fmaf(h2f((unsigned short)(q0 >> 16)), we, a11);                    \
  }
  for (; e + 2 <= e1; e += 2) { PN_EDGE(e) PN_EDGE(e + 1) }
  for (; e < e1; ++e) { PN_EDGE(e) }
#undef PN_EDGE
  const float bi = bias[c];
  a00 += bi; a01 += bi; a10 += bi; a11 += bi;

  if (has_bn) {
    float sv = a00 + a01 + (hi ? a10 + a11 : 0.f);
    float qv = a00 * a00 + a01 * a01 + (hi ? a10 * a10 + a11 * a11 : 0.f);
#pragma unroll
    for (int off = 32; off; off >>= 1) {
      sv += __shfl_xor(sv, off);
      qv += __shfl_xor(qv, off);
    }
    const float m   = sv * (1.f / 200.f);
    const float var = fmaf(qv, 1.f / 200.f, -m * m);
    const float scale = gamma[c] * rsqrtf(var + 1e-5f);
    const float shift = fmaf(-m, scale, beta[c]);
    unsigned short* out = (unsigned short*)outv;
    uint32_t no = (uint32_t)nout;
    float r0 = drop_mask_apply(fmaxf(fmaf(a00, scale, shift), 0.f), (uint32_t)l2,      (uint32_t)c, no, k0, k1);
    float r1 = drop_mask_apply(fmaxf(fmaf(a01, scale, shift), 0.f), (uint32_t)l2 + 1u, (uint32_t)c, no, k0, k1);
    *(uint32_t*)(out + (size_t)c * B_ + l2) = (uint32_t)f2h(r0) | ((uint32_t)f2h(r1) << 16);
    if (hi) {
      float r2 = drop_mask_apply(fmaxf(fmaf(a10, scale, shift), 0.f), (uint32_t)(128 + l2), (uint32_t)c, no, k0, k1);
      float r3 = drop_mask_apply(fmaxf(fmaf(a11, scale, shift), 0.f), (uint32_t)(129 + l2), (uint32_t)c, no, k0, k1);
      *(uint32_t*)(out + (size_t)c * B_ + 128 + l2) = (uint32_t)f2h(r2) | ((uint32_t)f2h(r3) << 16);
    }
  } else {
    float* out = (float*)outv;             // (B, 64) f32 final output
    out[(size_t)l2 * 64 + c]       = a00;
    out[(size_t)(l2 + 1) * 64 + c] = a01;
    if (hi) {
      out[(size_t)(128 + l2) * 64 + c] = a10;
      out[(size_t)(129 + l2) * 64 + c] = a11;
    }
  }
}

// ---------------- host ----------------
extern "C" void kernel_launch(void* const* d_in, const int* in_sizes, int n_in,
                              void* d_out, int out_size, void* d_ws, size_t ws_size,
                              hipStream_t stream) {
  (void)in_sizes; (void)n_in; (void)out_size; (void)ws_size;
  const float* x = (const float*)d_in[0];
  const int*   src[5]; const int* dst[5];
  const float* w[5];   const float* bias[5];
  const float* gamma[4]; const float* beta[4];
  int idx = 1;
  for (int l = 0; l < 5; ++l) {
    src[l]  = (const int*)d_in[idx++];
    dst[l]  = (const int*)d_in[idx++];
    w[l]    = (const float*)d_in[idx++];
    bias[l] = (const float*)d_in[idx++];
    if (l < 4) { gamma[l] = (const float*)d_in[idx++]; beta[l] = (const float*)d_in[idx++]; }
  }
  static const int NOUT[5] = {16384, 4096, 1024, 256, 64};

  // dkeys = jax.random.split(key(42), 4), partitionable threefry semantics
  uint32_t dk0[4], dk1[4];
  for (uint32_t i = 0; i < 4; ++i) tf2x32(0u, 42u, 0u, i, dk0[i], dk1[i]);

  // workspace carve
  char* ws = (char*)d_ws;
  size_t off = 0;
  auto carve = [&](size_t bytes) -> void* {
    void* p = ws + off;
    off = (off + bytes + 255) & ~(size_t)255;
    return p;
  };
  int* rp[5];
  for (int l = 0; l < 5; ++l) rp[l] = (int*)carve((size_t)(NOUT[l] + 1) * sizeof(int));
  unsigned short* h1 = (unsigned short*)carve((size_t)16384 * B_ * 2);
  unsigned short* h2 = (unsigned short*)carve((size_t)4096 * B_ * 2);
  unsigned short* h3 = (unsigned short*)carve((size_t)1024 * B_ * 2);
  unsigned short* h4 = (unsigned short*)carve((size_t)256 * B_ * 2);
  unsigned short* xT2 = (unsigned short*)carve((size_t)COLS * B_ * 2);

  float* kl = (float*)d_out + 12800;

  // 1: all row pointers + zero KL
  build_rp_all<<<(21829 + 255) / 256, 256, 0, stream>>>(
      dst[0], dst[1], dst[2], dst[3], dst[4],
      rp[0], rp[1], rp[2], rp[3], rp[4], kl);

  // 2: KL reduction (all layers)
  kl_all_kernel<<<256, 256, 0, stream>>>(w[0], w[1], w[2], w[3], w[4], kl);

  // 3: transpose -> fp16 xT
  transpose_rows_kernel<<<COLS / JT, 512, 0, stream>>>(x, xT2);

  // 4: layer 1 — wave-per-channel -> fp16 h1
  pool1_bn_wave<<<16384 / 4, 256, 0, stream>>>(
      xT2, src[0], w[0], bias[0], rp[0], gamma[0], beta[0], h1,
      dk0[0], dk1[0]);

  // 5-8: layers 2..5 — wave-per-channel, fp16 chain
  pooln_wave<<<4096 / 4, 256, 0, stream>>>(
      h1, src[1], w[1], bias[1], rp[1], gamma[1], beta[1], h2, 4096, 1,
      dk0[1], dk1[1]);
  pooln_wave<<<1024 / 4, 256, 0, stream>>>(
      h2, src[2], w[2], bias[2], rp[2], gamma[2], beta[2], h3, 1024, 1,
      dk0[2], dk1[2]);
  pooln_wave<<<256 / 4, 256, 0, stream>>>(
      h3, src[3], w[3], bias[3], rp[3], gamma[3], beta[3], h4, 256, 1,
      dk0[3], dk1[3]);
  pooln_wave<<<64 / 4, 256, 0, stream>>>(
      h4, src[4], w[4], bias[4], rp[4], nullptr, nullptr, (float*)d_out, 64, 0,
      0u, 0u);
}

// Round 12
// 109.363 us; speedup vs baseline: 1.6934x; 1.0455x over previous
//
#include <hip/hip_runtime.h>
#include <hip/hip_fp16.h>
#include <stdint.h>

#define B_    200
#define N0    65536
#define COLS  (N0 * 3)
#define JT    64
#define TPAD2 228   // ushorts; 228*2=456B row stride, 8B-aligned for uint2 reads

__device__ static inline unsigned short f2h(float f) {
  __half h = __float2half(f);              // RNE
  return *reinterpret_cast<unsigned short*>(&h);
}
__device__ static inline float h2f(unsigned short u) {
  __half h = *reinterpret_cast<__half*>(&u);
  return __half2float(h);
}

// ---------------- Threefry-2x32 (JAX-compatible, 20 rounds) ----------------
__host__ __device__ static inline void tf2x32(uint32_t k0, uint32_t k1,
                                              uint32_t x0, uint32_t x1,
                                              uint32_t& o0, uint32_t& o1) {
  const uint32_t ks2 = k0 ^ k1 ^ 0x1BD11BDAu;
  x0 += k0; x1 += k1;
#define TF_R(r) { x0 += x1; x1 = (x1 << (r)) | (x1 >> (32 - (r))); x1 ^= x0; }
  TF_R(13) TF_R(15) TF_R(26) TF_R(6)   x0 += k1;  x1 += ks2 + 1u;
  TF_R(17) TF_R(29) TF_R(16) TF_R(24)  x0 += ks2; x1 += k0  + 2u;
  TF_R(13) TF_R(15) TF_R(26) TF_R(6)   x0 += k0;  x1 += k1  + 3u;
  TF_R(17) TF_R(29) TF_R(16) TF_R(24)  x0 += k1;  x1 += ks2 + 4u;
  TF_R(13) TF_R(15) TF_R(26) TF_R(6)   x0 += ks2; x1 += k0  + 5u;
#undef TF_R
  o0 = x0; o1 = x1;
}

__device__ static inline float drop_mask_apply(float hn, uint32_t b, uint32_t c,
                                               uint32_t nout, uint32_t k0, uint32_t k1) {
  uint32_t o0, o1;
  tf2x32(k0, k1, 0u, b * nout + c, o0, o1);
  uint32_t bits = o0 ^ o1;
  float u = __uint_as_float((bits >> 9) | 0x3f800000u) - 1.0f;
  return (u < 0.9f) ? hn * (1.0f / 0.9f) : 0.0f;
}

// ---------------- all row_ptrs in one kernel (+ zero KL slot) ----------------
__global__ void build_rp_all(const int* __restrict__ dst0, const int* __restrict__ dst1,
                             const int* __restrict__ dst2, const int* __restrict__ dst3,
                             const int* __restrict__ dst4,
                             int* rp0, int* rp1, int* rp2, int* rp3, int* rp4,
                             float* kl) {
  int tid = blockIdx.x * blockDim.x + threadIdx.x;
  if (tid == 0) *kl = 0.f;
  if (tid >= 21829) return;
  const int starts[6] = {0, 16385, 20482, 21507, 21764, 21829};
  const int EDGa[5]   = {147456, 36864, 9216, 2304, 576};
  const int* dsts[5]  = {dst0, dst1, dst2, dst3, dst4};
  int* rps[5]         = {rp0, rp1, rp2, rp3, rp4};
  int l = 0;
  while (tid >= starts[l + 1]) ++l;
  int c = tid - starts[l];
  const int* dst = dsts[l];
  int lo = 0, hi = EDGa[l];
  while (lo < hi) { int mid = (lo + hi) >> 1; if (dst[mid] < c) lo = mid + 1; else hi = mid; }
  rps[l][c] = lo;
}

// ---------------- KL over all 5 weight tensors, one kernel ----------------
__global__ __launch_bounds__(256) void kl_all_kernel(
    const float* __restrict__ w0, const float* __restrict__ w1,
    const float* __restrict__ w2, const float* __restrict__ w3,
    const float* __restrict__ w4, float* __restrict__ out) {
  __shared__ float red[256];
  const float* ws[5] = {w0, w1, w2, w3, w4};
  const int    ns[5] = {442368, 36864, 9216, 2304, 576};
  int stride = gridDim.x * blockDim.x;
  int tid0 = blockIdx.x * blockDim.x + threadIdx.x;
  float s = 0.f;
#pragma unroll
  for (int l = 0; l < 5; ++l) {
    const float* w = ws[l];
    int n = ns[l];
    for (int i = tid0; i < n; i += stride) {
      float v = w[i];
      s += fmaf(0.5f * v, v, 999.5f);      // 0.5*(w*w-1) - (-1000)
    }
  }
  red[threadIdx.x] = s;
  __syncthreads();
  for (int st = 128; st > 0; st >>= 1) {
    if (threadIdx.x < st) red[threadIdx.x] += red[threadIdx.x + st];
    __syncthreads();
  }
  if (threadIdx.x == 0) atomicAdd(out, red[0]);
}

// ---------------- transpose: 64 j-cols x ALL 200 b, fp16 LDS ----------------
// blockIdx swizzled so each XCD streams a contiguous 1/8 of j-space.
__global__ __launch_bounds__(512, 4) void transpose_rows_kernel(
    const float* __restrict__ x, unsigned short* __restrict__ xT2) {
  __shared__ unsigned short tile[JT * TPAD2];
  const int t  = threadIdx.x;              // 0..511
  const int nb = COLS / JT;                // 3072, divisible by 8
  const int bid = (int)blockIdx.x;
  const int sb  = (bid & 7) * (nb >> 3) + (bid >> 3);   // XCD-bijective swizzle
  const int j0 = sb * JT;
  const int tx = t & 15;                   // j-quad: cols 4tx..4tx+3
  const int bl = t >> 4;                   // 0..31

  const float* xp = x + j0 + (tx << 2);
  float4 v[7];
#pragma unroll
  for (int p = 0; p < 7; ++p) {
    int b = bl + (p << 5);
    b = b < B_ ? b : B_ - 1;               // clamp (only pass 6 clamps)
    v[p] = *(const float4*)(xp + (size_t)b * COLS);
  }
  __builtin_amdgcn_sched_barrier(0);       // loads stay ABOVE all LDS stores
#pragma unroll
  for (int p = 0; p < 7; ++p) {
    int b = bl + (p << 5);
    if (b < B_) {                          // compile-time true for p<6
      int base = (tx << 2) * TPAD2 + b;
      tile[base            ] = f2h(v[p].x);
      tile[base +     TPAD2] = f2h(v[p].y);
      tile[base + 2 * TPAD2] = f2h(v[p].z);
      tile[base + 3 * TPAD2] = f2h(v[p].w);
    }
  }
  __syncthreads();
  // 64 rows x 50 uint2 (8B = 4 fp16) = 3200 stores, dense 400B rows
#pragma unroll
  for (int q = 0; q < 7; ++q) {
    unsigned idx = (unsigned)t + ((unsigned)q << 9);
    if (idx < 3200u) {
      unsigned row = idx / 50u;            // magic-mul, unsigned
      unsigned g   = idx - row * 50u;
      uint2 o = *(const uint2*)&tile[row * TPAD2 + (g << 2)];
      *(uint2*)(xT2 + (size_t)(j0 + row) * B_ + (g << 2)) = o;
    }
  }
}

// ---------------- layer-1 pool + BN + ReLU + dropout ----------------
// 256 thr = 4 waves: 2 channels x 2 edge-halves.  Lane l<50 owns batches
// 4l..4l+3 via uint2 (8B) gathers -> 3 loads/edge.  One LDS combine +
// single barrier; BN stats via shfl butterfly; fp16 packed output.
__global__ __launch_bounds__(256) void pool1_bn_wave(
    const unsigned short* __restrict__ xT2, const int* __restrict__ src,
    const float* __restrict__ w, const float* __restrict__ bias,
    const int* __restrict__ rp, const float* __restrict__ gamma,
    const float* __restrict__ beta, unsigned short* __restrict__ out,
    uint32_t k0, uint32_t k1) {
  __shared__ float part[2][64][4];
  const int l    = threadIdx.x & 63;
  const int wid  = threadIdx.x >> 6;
  const int chl  = wid & 1;
  const int half = wid >> 1;
  const int c    = ((int)blockIdx.x << 1) + chl;
  const bool act = (l < 50);
  const int b4   = (act ? l : 0) << 2;     // batches b4..b4+3

  float a0 = 0.f, a1 = 0.f, a2 = 0.f, a3 = 0.f;
  const int e1 = rp[c + 1];
  int e = rp[c] + half;
#define P1_EDGE(EE)                                                          \
  {                                                                          \
    const unsigned short* base = xT2 + (size_t)src[EE] * (3 * B_) + b4;      \
    float w0 = w[3 * (EE)], w1 = w[3 * (EE) + 1], w2 = w[3 * (EE) + 2];      \
    uint2 p0 = *(const uint2*)(base);                                        \
    uint2 p1 = *(const uint2*)(base + B_);                                   \
    uint2 p2 = *(const uint2*)(base + 2 * B_);                               \
    a0 = fmaf(h2f((unsigned short)p0.x), w0, a0);                            \
    a1 = fmaf(h2f((unsigned short)(p0.x >> 16)), w0, a1);                    \
    a2 = fmaf(h2f((unsigned short)p0.y), w0, a2);                            \
    a3 = fmaf(h2f((unsigned short)(p0.y >> 16)), w0, a3);                    \
    a0 = fmaf(h2f((unsigned short)p1.x), w1, a0);                            \
    a1 = fmaf(h2f((unsigned short)(p1.x >> 16)), w1, a1);                    \
    a2 = fmaf(h2f((unsigned short)p1.y), w1, a2);                            \
    a3 = fmaf(h2f((unsigned short)(p1.y >> 16)), w1, a3);                    \
    a0 = fmaf(h2f((unsigned short)p2.x), w2, a0);                            \
    a1 = fmaf(h2f((unsigned short)(p2.x >> 16)), w2, a1);                    \
    a2 = fmaf(h2f((unsigned short)p2.y), w2, a2);                            \
    a3 = fmaf(h2f((unsigned short)(p2.y >> 16)), w2, a3);                    \
  }
  for (; e + 2 < e1; e += 4) { P1_EDGE(e) P1_EDGE(e + 2) }
  for (; e < e1; e += 2) { P1_EDGE(e) }
#undef P1_EDGE

  if (half == 1) {
    part[chl][l][0] = a0; part[chl][l][1] = a1;
    part[chl][l][2] = a2; part[chl][l][3] = a3;
  }
  __syncthreads();
  if (half == 1) return;
  a0 += part[chl][l][0]; a1 += part[chl][l][1];
  a2 += part[chl][l][2]; a3 += part[chl][l][3];
  const float bi = bias[c];
  a0 += bi; a1 += bi; a2 += bi; a3 += bi;
  if (!act) { a0 = a1 = a2 = a3 = 0.f; }

  float sv = a0 + a1 + a2 + a3;
  float qv = a0 * a0 + a1 * a1 + a2 * a2 + a3 * a3;
#pragma unroll
  for (int off = 32; off; off >>= 1) {
    sv += __shfl_xor(sv, off);
    qv += __shfl_xor(qv, off);
  }
  const float m   = sv * (1.f / 200.f);
  const float var = fmaf(qv, 1.f / 200.f, -m * m);
  const float scale = gamma[c] * rsqrtf(var + 1e-5f);
  const float shift = fmaf(-m, scale, beta[c]);

  if (act) {
    float r0 = drop_mask_apply(fmaxf(fmaf(a0, scale, shift), 0.f), (uint32_t)b4,      (uint32_t)c, 16384u, k0, k1);
    float r1 = drop_mask_apply(fmaxf(fmaf(a1, scale, shift), 0.f), (uint32_t)b4 + 1u, (uint32_t)c, 16384u, k0, k1);
    float r2 = drop_mask_apply(fmaxf(fmaf(a2, scale, shift), 0.f), (uint32_t)b4 + 2u, (uint32_t)c, 16384u, k0, k1);
    float r3 = drop_mask_apply(fmaxf(fmaf(a3, scale, shift), 0.f), (uint32_t)b4 + 3u, (uint32_t)c, 16384u, k0, k1);
    uint2 pk;
    pk.x = (uint32_t)f2h(r0) | ((uint32_t)f2h(r1) << 16);
    pk.y = (uint32_t)f2h(r2) | ((uint32_t)f2h(r3) << 16);
    *(uint2*)(out + (size_t)c * B_ + b4) = pk;
  }
}

// ---------------- layers 2..5: 2 waves/channel, uint2 gathers ----------------
__global__ __launch_bounds__(256) void pooln_wave(
    const unsigned short* __restrict__ hin, const int* __restrict__ src,
    const float* __restrict__ w, const float* __restrict__ bias,
    const int* __restrict__ rp, const float* __restrict__ gamma,
    const float* __restrict__ beta, void* __restrict__ outv,
    int nout, int has_bn, uint32_t k0, uint32_t k1) {
  __shared__ float part[2][64][4];
  const int l    = threadIdx.x & 63;
  const int wid  = threadIdx.x >> 6;
  const int chl  = wid & 1;
  const int half = wid >> 1;
  const int c    = ((int)blockIdx.x << 1) + chl;
  const bool act = (l < 50);
  const int b4   = (act ? l : 0) << 2;

  float a0 = 0.f, a1 = 0.f, a2 = 0.f, a3 = 0.f;
  const int e1 = rp[c + 1];
  int e = rp[c] + half;
#define PN_EDGE(EE)                                                          \
  {                                                                          \
    const unsigned short* base = hin + (size_t)src[EE] * B_ + b4;            \
    float we = w[EE];                                                        \
    uint2 p0 = *(const uint2*)(base);                                        \
    a0 = fmaf(h2f((unsigned short)p0.x), we, a0);                            \
    a1 = fmaf(h2f((unsigned short)(p0.x >> 16)), we, a1);                    \
    a2 = fmaf(h2f((unsigned short)p0.y), we, a2);                            \
    a3 = fmaf(h2f((unsigned short)(p0.y >> 16)), we, a3);                    \
  }
  for (; e + 2 < e1; e += 4) { PN_EDGE(e) PN_EDGE(e + 2) }
  for (; e < e1; e += 2) { PN_EDGE(e) }
#undef PN_EDGE

  if (half == 1) {
    part[chl][l][0] = a0; part[chl][l][1] = a1;
    part[chl][l][2] = a2; part[chl][l][3] = a3;
  }
  __syncthreads();
  if (half == 1) return;
  a0 += part[chl][l][0]; a1 += part[chl][l][1];
  a2 += part[chl][l][2]; a3 += part[chl][l][3];
  const float bi = bias[c];
  a0 += bi; a1 += bi; a2 += bi; a3 += bi;

  if (has_bn) {
    if (!act) { a0 = a1 = a2 = a3 = 0.f; }
    float sv = a0 + a1 + a2 + a3;
    float qv = a0 * a0 + a1 * a1 + a2 * a2 + a3 * a3;
#pragma unroll
    for (int off = 32; off; off >>= 1) {
      sv += __shfl_xor(sv, off);
      qv += __shfl_xor(qv, off);
    }
    const float m   = sv * (1.f / 200.f);
    const float var = fmaf(qv, 1.f / 200.f, -m * m);
    const float scale = gamma[c] * rsqrtf(var + 1e-5f);
    const float shift = fmaf(-m, scale, beta[c]);
    if (act) {
      unsigned short* out = (unsigned short*)outv;
      uint32_t no = (uint32_t)nout;
      float r0 = drop_mask_apply(fmaxf(fmaf(a0, scale, shift), 0.f), (uint32_t)b4,      (uint32_t)c, no, k0, k1);
      float r1 = drop_mask_apply(fmaxf(fmaf(a1, scale, shift), 0.f), (uint32_t)b4 + 1u, (uint32_t)c, no, k0, k1);
      float r2 = drop_mask_apply(fmaxf(fmaf(a2, scale, shift), 0.f), (uint32_t)b4 + 2u, (uint32_t)c, no, k0, k1);
      float r3 = drop_mask_apply(fmaxf(fmaf(a3, scale, shift), 0.f), (uint32_t)b4 + 3u, (uint32_t)c, no, k0, k1);
      uint2 pk;
      pk.x = (uint32_t)f2h(r0) | ((uint32_t)f2h(r1) << 16);
      pk.y = (uint32_t)f2h(r2) | ((uint32_t)f2h(r3) << 16);
      *(uint2*)(out + (size_t)c * B_ + b4) = pk;
    }
  } else if (act) {
    float* out = (float*)outv;             // (B, 64) f32 final output
    out[(size_t)(b4    ) * 64 + c] = a0;
    out[(size_t)(b4 + 1) * 64 + c] = a1;
    out[(size_t)(b4 + 2) * 64 + c] = a2;
    out[(size_t)(b4 + 3) * 64 + c] = a3;
  }
}

// ---------------- host ----------------
extern "C" void kernel_launch(void* const* d_in, const int* in_sizes, int n_in,
                              void* d_out, int out_size, void* d_ws, size_t ws_size,
                              hipStream_t stream) {
  (void)in_sizes; (void)n_in; (void)out_size; (void)ws_size;
  const float* x = (const float*)d_in[0];
  const int*   src[5]; const int* dst[5];
  const float* w[5];   const float* bias[5];
  const float* gamma[4]; const float* beta[4];
  int idx = 1;
  for (int l = 0; l < 5; ++l) {
    src[l]  = (const int*)d_in[idx++];
    dst[l]  = (const int*)d_in[idx++];
    w[l]    = (const float*)d_in[idx++];
    bias[l] = (const float*)d_in[idx++];
    if (l < 4) { gamma[l] = (const float*)d_in[idx++]; beta[l] = (const float*)d_in[idx++]; }
  }
  static const int NOUT[5] = {16384, 4096, 1024, 256, 64};

  // dkeys = jax.random.split(key(42), 4), partitionable threefry semantics
  uint32_t dk0[4], dk1[4];
  for (uint32_t i = 0; i < 4; ++i) tf2x32(0u, 42u, 0u, i, dk0[i], dk1[i]);

  // workspace carve
  char* ws = (char*)d_ws;
  size_t off = 0;
  auto carve = [&](size_t bytes) -> void* {
    void* p = ws + off;
    off = (off + bytes + 255) & ~(size_t)255;
    return p;
  };
  int* rp[5];
  for (int l = 0; l < 5; ++l) rp[l] = (int*)carve((size_t)(NOUT[l] + 1) * sizeof(int));
  unsigned short* h1 = (unsigned short*)carve((size_t)16384 * B_ * 2);
  unsigned short* h2 = (unsigned short*)carve((size_t)4096 * B_ * 2);
  unsigned short* h3 = (unsigned short*)carve((size_t)1024 * B_ * 2);
  unsigned short* h4 = (unsigned short*)carve((size_t)256 * B_ * 2);
  unsigned short* xT2 = (unsigned short*)carve((size_t)COLS * B_ * 2);

  float* kl = (float*)d_out + 12800;

  // 1: all row pointers + zero KL
  build_rp_all<<<(21829 + 255) / 256, 256, 0, stream>>>(
      dst[0], dst[1], dst[2], dst[3], dst[4],
      rp[0], rp[1], rp[2], rp[3], rp[4], kl);

  // 2: KL reduction (all layers)
  kl_all_kernel<<<256, 256, 0, stream>>>(w[0], w[1], w[2], w[3], w[4], kl);

  // 3: transpose -> fp16 xT (XCD-swizzled grid)
  transpose_rows_kernel<<<COLS / JT, 512, 0, stream>>>(x, xT2);

  // 4: layer 1 — 2 waves/channel -> fp16 h1
  pool1_bn_wave<<<16384 / 2, 256, 0, stream>>>(
      xT2, src[0], w[0], bias[0], rp[0], gamma[0], beta[0], h1,
      dk0[0], dk1[0]);

  // 5-8: layers 2..5 — 2 waves/channel, fp16 chain
  pooln_wave<<<4096 / 2, 256, 0, stream>>>(
      h1, src[1], w[1], bias[1], rp[1], gamma[1], beta[1], h2, 4096, 1,
      dk0[1], dk1[1]);
  pooln_wave<<<1024 / 2, 256, 0, stream>>>(
      h2, src[2], w[2], bias[2], rp[2], gamma[2], beta[2], h3, 1024, 1,
      dk0[2], dk1[2]);
  pooln_wave<<<256 / 2, 256, 0, stream>>>(
      h3, src[3], w[3], bias[3], rp[3], gamma[3], beta[3], h4, 256, 1,
      dk0[3], dk1[3]);
  pooln_wave<<<64 / 2, 256, 0, stream>>>(
      h4, src[4], w[4], bias[4], rp[4], nullptr, nullptr, (float*)d_out, 64, 0,
      0u, 0u);
}